// Round 13
// baseline (2448.130 us; speedup 1.0000x reference)
//
#include <hip/hip_runtime.h>
#include <cmath>

#define NN 100000
#define NE 1600000
#define NG 512
#define H 200
#define D 205
#define EPSV 1e-5f
#define SCAN_B 1024
#define KP 224    // weight (B-side) k-pitch, bf16, zero-padded
#define LPH 208   // node-buffer k-pitch (bf16 hi/lo pairs)

typedef __attribute__((ext_vector_type(8))) short short8v;
typedef __attribute__((ext_vector_type(4))) float f32x4;

#define MFMA16(a,b,c) __builtin_amdgcn_mfma_f32_16x16x32_bf16(a,b,c,0,0,0)

static __device__ __forceinline__ float sigm(float x){ return 1.0f/(1.0f+expf(-x)); }

// split fp32 -> bf16 hi (truncate) + bf16 lo (residual)
static __device__ __forceinline__ void split2(float x, unsigned short& h, unsigned short& l){
  unsigned xb = __float_as_uint(x);
  h = (unsigned short)(xb >> 16);
  float hf = __uint_as_float(xb & 0xffff0000u);
  l = (unsigned short)(__float_as_uint(x - hf) >> 16);
}

static __device__ __forceinline__ float uf(unsigned short u){
  return __uint_as_float(((unsigned)u) << 16);
}

static __device__ __forceinline__ void gload16(const void* src, void* dst){
  __builtin_amdgcn_global_load_lds(
      (const __attribute__((address_space(1))) unsigned int*)src,
      (__attribute__((address_space(3))) unsigned int*)dst, 16, 0, 0);
}

// ---------------- cvt fp32 [rows,C] -> hi/lo bf16 [rows,P], zero-padded ----------------
__global__ __launch_bounds__(256) void cvt_split(const float* __restrict__ in,
    unsigned short* __restrict__ hi, unsigned short* __restrict__ lo, int rows, int C, int P){
  long i = (long)blockIdx.x*256 + threadIdx.x;
  long tot = (long)rows*P;
  if (i >= tot) return;
  int r = (int)(i/P), c = (int)(i - (long)r*P);
  float v = (c < C) ? in[(size_t)r*C + c] : 0.f;
  unsigned short hh, ll; split2(v,hh,ll);
  hi[i] = hh; lo[i] = ll;
}

// ---------------- cvt + transpose: out[n][k]=in[k][n], [C,KP], zero-padded ----------------
__global__ __launch_bounds__(256) void cvt_tsplit(const float* __restrict__ in,
    unsigned short* __restrict__ hi, unsigned short* __restrict__ lo, int R, int C){
  int i = blockIdx.x*256 + threadIdx.x;
  if (i >= C*KP) return;
  int n = i/KP, k = i - n*KP;
  float v = (k < R) ? in[(size_t)k*C + n] : 0.f;
  unsigned short hh, ll; split2(v,hh,ll);
  hi[i] = hh; lo[i] = ll;
}

// ---------------- split-bf16 MFMA GEMM: C = (Ahi+Alo) @ (Bhi+Blo)^T, 3-term ----------------
// (round-12 verbatim; A direct, B in LDS)
template<int EPIL>
__global__ __launch_bounds__(256) void mgemm(
    const unsigned short* __restrict__ Ahi, const unsigned short* __restrict__ Alo,
    const unsigned short* __restrict__ Bhi, const unsigned short* __restrict__ Blo,
    int M, int N, int nj, int npan,
    const float* __restrict__ bias,
    const float* __restrict__ bg, const float* __restrict__ bb,
    const float* __restrict__ bm, const float* __restrict__ bv,
    unsigned short* __restrict__ Chi, unsigned short* __restrict__ Clo)
{
  __shared__ __align__(16) char S[16384];   // Bhi 0..8K, Blo 8K..16K (granule-major)
  const int bid = blockIdx.x;
  const int xcd = bid & 7, sl = bid >> 3;
  const int pl = sl / nj, jj = sl - pl*nj;
  const int p = pl*8 + xcd;
  if (p >= npan) return;
  const int n0 = jj*128, r0 = p*128;
  const int tid = threadIdx.x, lane = tid & 63, wave = tid >> 6;
  const int wr = (wave>>1)*64, wc = (wave&1)*64;
  const int fr = lane & 15, fq = lane >> 4;
  f32x4 acc[4][4] = {};

  const unsigned short* sp[4]; int sdst[4];
  #pragma unroll
  for (int i = 0; i < 4; ++i) {
    int g = wave + 4*i;                 // 0..15
    int region = g >> 3, c = g & 7, rowgrp = c >> 2, q = c & 3;
    int row = rowgrp*64 + lane;
    int rg = n0 + row; if (rg > N-1) rg = N-1;
    sp[i] = (region ? Blo : Bhi) + (size_t)rg*KP + q*8;
    sdst[i] = region*8192 + q*2048 + rowgrp*1024;
  }
  int arow[4];
  #pragma unroll
  for (int t = 0; t < 4; ++t) {
    int rg = r0 + wr + t*16 + fr; if (rg > M-1) rg = M-1;
    arow[t] = rg*LPH + fq*8;
  }

  for (int k0 = 0; k0 < KP; k0 += 32) {
    #pragma unroll
    for (int i = 0; i < 4; ++i) gload16(sp[i] + k0, S + sdst[i]);
    __syncthreads();
    short8v ah[4], al[4], bh[4], bl[4];
    #pragma unroll
    for (int t = 0; t < 4; ++t) {
      ah[t] = *(const short8v*)(Ahi + arow[t] + k0);
      al[t] = *(const short8v*)(Alo + arow[t] + k0);
      int rb = (wc + t*16 + fr)*16;
      bh[t] = *(const short8v*)(S +    0 + fq*2048 + rb);
      bl[t] = *(const short8v*)(S + 8192 + fq*2048 + rb);
    }
    #pragma unroll
    for (int i = 0; i < 4; ++i)
      #pragma unroll
      for (int j = 0; j < 4; ++j) {
        acc[i][j] = MFMA16(ah[i], bh[j], acc[i][j]);
        acc[i][j] = MFMA16(ah[i], bl[j], acc[i][j]);
        acc[i][j] = MFMA16(al[i], bh[j], acc[i][j]);
      }
    __syncthreads();
  }

  #pragma unroll
  for (int i = 0; i < 4; ++i)
    #pragma unroll
    for (int j = 0; j < 4; ++j)
      #pragma unroll
      for (int q = 0; q < 4; ++q) {
        int row = r0 + wr + i*16 + fq*4 + q;
        int col = n0 + wc + j*16 + fr;
        if (row < M && col < N) {
          float c = acc[i][j][q];
          if (EPIL) {
            c += bias[col];
            c = (c - bm[col]) * (bg[col] * rsqrtf(bv[col] + EPSV)) + bb[col];
            c = fmaxf(c, 0.f);
          }
          unsigned short hh, ll; split2(c, hh, ll);
          size_t o = (size_t)row*LPH + col;
          Chi[o] = hh; Clo[o] = ll;
        }
      }
}

// ---------------- fused GRU: BARRIER-FREE — W fragments direct global->VGPR (L2-hot) ----
// ONLY change vs round-12: LDS staging + both __syncthreads removed; W fragment loads use
// the inverse of the old LDS layout map: row = g3*H + clamp(j0+jj), 16B granule fq.
// No inter-thread communication remains -> no race surface; 4-acc form kept.
__global__ __launch_bounds__(256, 3) void gru6(
    const unsigned short* __restrict__ Ghi, const unsigned short* __restrict__ Glo,
    const unsigned short* __restrict__ Hhi, const unsigned short* __restrict__ Hlo,
    const unsigned short* __restrict__ Wihh, const unsigned short* __restrict__ Wihl,
    const unsigned short* __restrict__ Whhh, const unsigned short* __restrict__ Whhl,
    const float* __restrict__ bih, const float* __restrict__ bhh,
    int nj, int npan,
    unsigned short* __restrict__ Ohi, unsigned short* __restrict__ Olo)
{
  const int bid = blockIdx.x;
  const int xcd = bid & 7, sl = bid >> 3;
  const int pl = sl / nj, jt = sl - pl*nj;
  const int p = pl*8 + xcd;
  if (p >= npan) return;
  const int j0 = jt*32, r0 = p*128;
  const int tid = threadIdx.x, lane = tid & 63, wave = tid >> 6;
  const int fr = lane & 15, fq = lane >> 4;
  f32x4 acc[4][2][2] = {};   // [0]=r(i+h), [1]=z(i+h), [2]=n-in, [3]=n-hid

  // W fragment element-offsets (k0-invariant): rows j0+fr and j0+fr+16 per gate, clamped
  int woff0[6], woff1[6];
  #pragma unroll
  for (int g = 0; g < 6; ++g) {
    int g3 = (g >= 3) ? g-3 : g;
    int jc0 = j0 + fr;      if (jc0 > H-1) jc0 = H-1;
    int jc1 = j0 + fr + 16; if (jc1 > H-1) jc1 = H-1;
    woff0[g] = (g3*H + jc0)*KP + fq*8;
    woff1[g] = (g3*H + jc1)*KP + fq*8;
  }
  // A fragment element-offsets (k0-invariant)
  int arow[2];
  #pragma unroll
  for (int t = 0; t < 2; ++t) {
    int rg = r0 + wave*32 + t*16 + fr; if (rg > NN-1) rg = NN-1;
    arow[t] = rg*LPH + fq*8;
  }

  #pragma unroll
  for (int k0 = 0; k0 < KP; k0 += 32) {
    short8v A[4][2];   // [comp: g-hi, g-lo, h-hi, h-lo][t]
    #pragma unroll
    for (int t = 0; t < 2; ++t) {
      A[0][t] = *(const short8v*)(Ghi + arow[t] + k0);
      A[1][t] = *(const short8v*)(Glo + arow[t] + k0);
      A[2][t] = *(const short8v*)(Hhi + arow[t] + k0);
      A[3][t] = *(const short8v*)(Hlo + arow[t] + k0);
    }
    #pragma unroll
    for (int g = 0; g < 6; ++g) {
      const unsigned short* wbh = (g < 3) ? Wihh : Whhh;
      const unsigned short* wbl = (g < 3) ? Wihl : Whhl;
      short8v b0h = *(const short8v*)(wbh + woff0[g] + k0);
      short8v b1h = *(const short8v*)(wbh + woff1[g] + k0);
      short8v b0l = *(const short8v*)(wbl + woff0[g] + k0);
      short8v b1l = *(const short8v*)(wbl + woff1[g] + k0);
      const int ai = (g < 3) ? 0 : 2;               // input path vs hidden path
      const int ac = (g == 5) ? 3 : (g % 3);        // r,z shared; n-in=2, n-hid=3
      #pragma unroll
      for (int t = 0; t < 2; ++t) {
        acc[ac][t][0] = MFMA16(A[ai][t],   b0h, acc[ac][t][0]);
        acc[ac][t][0] = MFMA16(A[ai][t],   b0l, acc[ac][t][0]);
        acc[ac][t][0] = MFMA16(A[ai+1][t], b0h, acc[ac][t][0]);
        acc[ac][t][1] = MFMA16(A[ai][t],   b1h, acc[ac][t][1]);
        acc[ac][t][1] = MFMA16(A[ai][t],   b1l, acc[ac][t][1]);
        acc[ac][t][1] = MFMA16(A[ai+1][t], b1h, acc[ac][t][1]);
      }
    }
  }

  #pragma unroll
  for (int ct = 0; ct < 2; ++ct) {
    int j = j0 + ct*16 + fr;
    if (j >= H) continue;
    float br  = bih[j]     + bhh[j];
    float bz  = bih[H+j]   + bhh[H+j];
    float bin = bih[2*H+j], bhn = bhh[2*H+j];
    #pragma unroll
    for (int t = 0; t < 2; ++t)
      #pragma unroll
      for (int q = 0; q < 4; ++q) {
        int row = r0 + wave*32 + t*16 + fq*4 + q;
        if (row >= NN) continue;
        float rv = sigm(acc[0][t][ct][q] + br);
        float zv = sigm(acc[1][t][ct][q] + bz);
        float nv = tanhf(acc[2][t][ct][q] + bin + rv*(acc[3][t][ct][q] + bhn));
        size_t o = (size_t)row*LPH + j;
        float ho = uf(Hhi[o]) + uf(Hlo[o]);
        unsigned short hh2, ll2; split2((1.f - zv)*nv + zv*ho, hh2, ll2);
        Ohi[o] = hh2; Olo[o] = ll2;
      }
  }
}

// ---------------- CSR build ----------------
__global__ __launch_bounds__(256) void hist_k(const int* __restrict__ dst, int* __restrict__ deg){
  int e = blockIdx.x*256 + threadIdx.x;
  if (e < NE) atomicAdd(&deg[dst[e]], 1);
}

__global__ __launch_bounds__(256) void scan1_k(const int* __restrict__ deg, int* __restrict__ part,
                                               int* __restrict__ bsum, int n){
  __shared__ int lds[256];
  int t = threadIdx.x;
  int base = blockIdx.x * SCAN_B + t*4;
  int v[4]; int s = 0;
  #pragma unroll
  for (int q = 0; q < 4; ++q){ int idx = base+q; v[q] = (idx < n) ? deg[idx] : 0; s += v[q]; }
  lds[t] = s;
  __syncthreads();
  for (int off = 1; off < 256; off <<= 1){
    int val = 0;
    if (t >= off) val = lds[t-off];
    __syncthreads();
    if (t >= off) lds[t] += val;
    __syncthreads();
  }
  if (t == 255) bsum[blockIdx.x] = lds[255];
  int run = (t == 0) ? 0 : lds[t-1];
  #pragma unroll
  for (int q = 0; q < 4; ++q){ int idx = base+q; if (idx < n) part[idx] = run; run += v[q]; }
}

__global__ void scan2_k(int* __restrict__ bsum, int nb){
  __shared__ int lds[128];
  int t = threadIdx.x;
  int v = (t < nb) ? bsum[t] : 0;
  lds[t] = v;
  __syncthreads();
  for (int off = 1; off < 128; off <<= 1){
    int val = 0;
    if (t >= off) val = lds[t-off];
    __syncthreads();
    if (t >= off) lds[t] += val;
    __syncthreads();
  }
  if (t < nb) bsum[t] = (t == 0) ? 0 : lds[t-1];
}

__global__ __launch_bounds__(256) void scan3_k(const int* __restrict__ part, const int* __restrict__ bsum,
                                               int* __restrict__ rowptr, int* __restrict__ cpos, int n){
  int i = blockIdx.x*256 + threadIdx.x;
  if (i < n){
    int v = part[i] + bsum[i >> 10];
    rowptr[i] = v;
    cpos[i] = v;
  }
  if (i == 0) rowptr[n] = NE;
}

__global__ __launch_bounds__(256) void fill_k(const int* __restrict__ src, const int* __restrict__ dst,
                                              int* __restrict__ cpos, int* __restrict__ elist){
  int e = blockIdx.x*256 + threadIdx.x;
  if (e < NE){
    int p = atomicAdd(&cpos[dst[e]], 1);
    elist[p] = src[e];
  }
}

// ---------------- gather: agg[n] = sum m[src]; LDS-preloaded indices + 4-way ILP ----------------
__global__ __launch_bounds__(256) void gather_k(const unsigned short* __restrict__ mhi,
                                                const unsigned short* __restrict__ mlo,
                                                const int* __restrict__ rowptr,
                                                const int* __restrict__ elist,
                                                unsigned short* __restrict__ ahi,
                                                unsigned short* __restrict__ alo){
  __shared__ int sIdx[256];
  int n = blockIdx.x;
  int beg = rowptr[n], end = rowptr[n+1];
  int j = threadIdx.x;
  float a0=0.f, a1=0.f, a2=0.f, a3=0.f;
  for (int c0 = beg; c0 < end; c0 += 256){
    int cnt = min(256, end - c0);
    __syncthreads();
    if (threadIdx.x < cnt) sIdx[threadIdx.x] = elist[c0 + threadIdx.x];
    __syncthreads();
    if (j < H){
      int k = 0;
      for (; k + 4 <= cnt; k += 4){
        size_t s0 = (size_t)sIdx[k  ]*LPH + j;
        size_t s1 = (size_t)sIdx[k+1]*LPH + j;
        size_t s2 = (size_t)sIdx[k+2]*LPH + j;
        size_t s3 = (size_t)sIdx[k+3]*LPH + j;
        a0 += uf(mhi[s0]) + uf(mlo[s0]);
        a1 += uf(mhi[s1]) + uf(mlo[s1]);
        a2 += uf(mhi[s2]) + uf(mlo[s2]);
        a3 += uf(mhi[s3]) + uf(mlo[s3]);
      }
      for (; k < cnt; ++k){
        size_t s = (size_t)sIdx[k]*LPH + j;
        a0 += uf(mhi[s]) + uf(mlo[s]);
      }
    }
  }
  if (j < H){
    unsigned short hh, ll; split2((a0 + a1) + (a2 + a3), hh, ll);
    size_t o = (size_t)n*LPH + j;
    ahi[o] = hh; alo[o] = ll;
  }
}

// ---------------- pooling: one block per graph (batch sorted) ----------------
__global__ __launch_bounds__(256) void pool_g(
    const unsigned short* __restrict__ hhi, const unsigned short* __restrict__ hlo,
    const int* __restrict__ batch,
    const float* __restrict__ g2, const float* __restrict__ b2,
    const float* __restrict__ m2, const float* __restrict__ v2,
    float* __restrict__ gmean, float* __restrict__ gmax)
{
  int g = blockIdx.x;
  int lo = 0, hi = NN;
  while (lo < hi){ int mid = (lo+hi)>>1; if (batch[mid] < g) lo = mid+1; else hi = mid; }
  int lo2 = lo, hi2 = NN;
  while (lo2 < hi2){ int mid = (lo2+hi2)>>1; if (batch[mid] < g+1) lo2 = mid+1; else hi2 = mid; }
  int j = threadIdx.x;
  if (j >= H) return;
  float s = g2[j] * rsqrtf(v2[j] + EPSV);
  float mm = m2[j], bb = b2[j];
  float sum = 0.f, mx = 0.f;
  for (int n = lo; n < hi2; ++n){
    size_t o = (size_t)n*LPH + j;
    float hv = uf(hhi[o]) + uf(hlo[o]);
    float val = fmaxf((hv - mm)*s + bb, 0.f);
    sum += val;
    mx = fmaxf(mx, val);
  }
  int c = hi2 - lo;
  gmean[g*H + j] = (c > 0) ? sum/(float)c : 0.f;
  gmax [g*H + j] = mx;
}

// ---------------- fc1 + bnf + relu ----------------
__global__ __launch_bounds__(256) void fc1_k(
    const float* __restrict__ gmean, const float* __restrict__ gmax,
    const float* __restrict__ W,
    const float* __restrict__ bias,
    const float* __restrict__ fg, const float* __restrict__ fb,
    const float* __restrict__ fm, const float* __restrict__ fv,
    float* __restrict__ out)
{
  int tid = blockIdx.x*256 + threadIdx.x;
  if (tid >= NG*H) return;
  int g = tid / H, j = tid - g*H;
  const float* wr = W + j*2*H;
  float acc = bias[j];
  for (int k = 0; k < H; ++k) acc += gmean[g*H + k] * wr[k];
  for (int k = 0; k < H; ++k) acc += gmax[g*H + k] * wr[H + k];
  float s = fg[j] * rsqrtf(fv[j] + EPSV);
  acc = (acc - fm[j]) * s + fb[j];
  out[tid] = fmaxf(acc, 0.f);
}

__global__ void fc2_k(const float* __restrict__ in, const float* __restrict__ W,
                      const float* __restrict__ bias, float* __restrict__ out)
{
  int tid = blockIdx.x*256 + threadIdx.x;
  if (tid >= NG*2) return;
  int g = tid >> 1, c = tid & 1;
  float acc = bias[c];
  const float* wr = W + c*H;
  const float* xr = in + g*H;
  for (int k = 0; k < H; ++k) acc += xr[k]*wr[k];
  out[tid] = acc;
}

extern "C" void kernel_launch(void* const* d_in, const int* in_sizes, int n_in,
                              void* d_out, int out_size, void* d_ws, size_t ws_size,
                              hipStream_t stream)
{
  const float* x     = (const float*)d_in[0];
  const int*   eidx  = (const int*)d_in[1];
  const int*   batch = (const int*)d_in[2];
  const float* projW = (const float*)d_in[3];
  const float* projb = (const float*)d_in[4];
  const float* bn1g  = (const float*)d_in[5];
  const float* bn1b  = (const float*)d_in[6];
  const float* bn1m  = (const float*)d_in[7];
  const float* bn1v  = (const float*)d_in[8];
  const float* bn2g  = (const float*)d_in[9];
  const float* bn2b  = (const float*)d_in[10];
  const float* bn2m  = (const float*)d_in[11];
  const float* bn2v  = (const float*)d_in[12];
  const float* bnfg  = (const float*)d_in[13];
  const float* bnfb  = (const float*)d_in[14];
  const float* bnfm  = (const float*)d_in[15];
  const float* bnfv  = (const float*)d_in[16];
  const float* ggcW  = (const float*)d_in[17];
  const float* wih   = (const float*)d_in[18];
  const float* whh   = (const float*)d_in[19];
  const float* bih   = (const float*)d_in[20];
  const float* bhh   = (const float*)d_in[21];
  const float* fc1W  = (const float*)d_in[22];
  const float* fc1b  = (const float*)d_in[23];
  const float* fc2W  = (const float*)d_in[24];
  const float* fc2b  = (const float*)d_in[25];

  char* wsp = (char*)d_ws;
  auto alloc = [&](size_t nbytes) {
    char* p = wsp;
    wsp += ((nbytes + 255) / 256) * 256;
    return (void*)p;
  };
  // node-tensor bf16 hi/lo pairs, pitch LPH=208; xa pair doubles as x-input then agg
  unsigned short* xaHi = (unsigned short*)alloc((size_t)NN*LPH*2);
  unsigned short* xaLo = (unsigned short*)alloc((size_t)NN*LPH*2);
  unsigned short* hHi  = (unsigned short*)alloc((size_t)NN*LPH*2);
  unsigned short* hLo  = (unsigned short*)alloc((size_t)NN*LPH*2);
  unsigned short* mHi  = (unsigned short*)alloc((size_t)NN*LPH*2);
  unsigned short* mLo  = (unsigned short*)alloc((size_t)NN*LPH*2);
  // weights (bf16 split, zero-padded to KP)
  unsigned short* pBh   = (unsigned short*)alloc((size_t)H*KP*2);
  unsigned short* pBl   = (unsigned short*)alloc((size_t)H*KP*2);
  unsigned short* wihBh = (unsigned short*)alloc((size_t)3*H*KP*2);
  unsigned short* wihBl = (unsigned short*)alloc((size_t)3*H*KP*2);
  unsigned short* whhBh = (unsigned short*)alloc((size_t)3*H*KP*2);
  unsigned short* whhBl = (unsigned short*)alloc((size_t)3*H*KP*2);
  unsigned short* gBh[3]; unsigned short* gBl[3];
  for (int i = 0; i < 3; ++i) {
    gBh[i] = (unsigned short*)alloc((size_t)H*KP*2);
    gBl[i] = (unsigned short*)alloc((size_t)H*KP*2);
  }
  float* gmean = (float*)alloc((size_t)NG*H*4);
  float* gmax  = (float*)alloc((size_t)NG*H*4);
  float* fc1o  = (float*)alloc((size_t)NG*H*4);
  const int NB = (NN + SCAN_B - 1) / SCAN_B;
  int* deg    = (int*)alloc((size_t)NN*4);
  int* part   = (int*)alloc((size_t)NN*4);
  int* bsum   = (int*)alloc((size_t)NB*4);
  int* rowptr = (int*)alloc((size_t)(NN+1)*4);
  int* cpos   = (int*)alloc((size_t)NN*4);
  int* elist  = (int*)alloc((size_t)NE*4);

  const int* srcp = eidx;
  const int* dstp = eidx + NE;

  // ---- CSR build (reused all 3 steps) ----
  hipMemsetAsync(deg, 0, (size_t)NN*4, stream);
  hist_k<<<(NE + 255)/256, 256, 0, stream>>>(dstp, deg);
  scan1_k<<<NB, 256, 0, stream>>>(deg, part, bsum, NN);
  scan2_k<<<1, 128, 0, stream>>>(bsum, NB);
  scan3_k<<<(NN + 255)/256, 256, 0, stream>>>(part, bsum, rowptr, cpos, NN);
  fill_k<<<(NE + 255)/256, 256, 0, stream>>>(srcp, dstp, cpos, elist);

  // ---- weight splits (pitch KP, zero-padded) ----
  cvt_split<<<(int)(((long)H*KP + 255)/256), 256, 0, stream>>>(projW, pBh, pBl, H, D, KP);
  cvt_split<<<(int)(((long)3*H*KP + 255)/256), 256, 0, stream>>>(wih, wihBh, wihBl, 3*H, H, KP);
  cvt_split<<<(int)(((long)3*H*KP + 255)/256), 256, 0, stream>>>(whh, whhBh, whhBl, 3*H, H, KP);
  for (int i = 0; i < 3; ++i)
    cvt_tsplit<<<(H*KP + 255)/256, 256, 0, stream>>>(ggcW + (size_t)i*H*H, gBh[i], gBl[i], H, H);

  // ---- x -> split pair (pitch LPH, zero-padded) ----
  cvt_split<<<(int)(((long)NN*LPH + 255)/256), 256, 0, stream>>>(x, xaHi, xaLo, NN, D, LPH);

  // XCD-grouped grids
  const int NPAN = (NN + 127)/128;            // 782
  const int PL8  = (NPAN + 7)/8;              // 98
  const int NJ_G = (H + 127)/128;             // 2
  const int NJ_U = (H + 31)/32;               // 7
  const int GRID_G = 8 * NJ_G * PL8;
  const int GRID_U = 8 * NJ_U * PL8;

  // proj + bn1 + relu : xpair -> hpair
  mgemm<1><<<GRID_G, 256, 0, stream>>>(xaHi, xaLo, pBh, pBl, NN, H, NJ_G, NPAN,
                                       projb, bn1g, bn1b, bn1m, bn1v, hHi, hLo);

  unsigned short *chHi = hHi, *chLo = hLo, *cmHi = mHi, *cmLo = mLo;
  for (int i = 0; i < 3; ++i) {
    mgemm<0><<<GRID_G, 256, 0, stream>>>(chHi, chLo, gBh[i], gBl[i], NN, H, NJ_G, NPAN,
                                         nullptr, nullptr, nullptr, nullptr, nullptr,
                                         cmHi, cmLo);
    gather_k<<<NN, 256, 0, stream>>>(cmHi, cmLo, rowptr, elist, xaHi, xaLo);
    gru6<<<GRID_U, 256, 0, stream>>>(xaHi, xaLo, chHi, chLo,
                                     wihBh, wihBl, whhBh, whhBl,
                                     bih, bhh, NJ_U, NPAN, cmHi, cmLo);
    unsigned short* t;
    t = chHi; chHi = cmHi; cmHi = t;
    t = chLo; chLo = cmLo; cmLo = t;
  }

  pool_g<<<NG, 256, 0, stream>>>(chHi, chLo, batch, bn2g, bn2b, bn2m, bn2v, gmean, gmax);
  fc1_k<<<(NG*H + 255)/256, 256, 0, stream>>>(gmean, gmax, fc1W, fc1b,
                                              bnfg, bnfb, bnfm, bnfv, fc1o);
  fc2_k<<<(NG*2 + 255)/256, 256, 0, stream>>>(fc1o, fc2W, fc2b, (float*)d_out);
}

// Round 15
// 2121.812 us; speedup vs baseline: 1.1538x; 1.1538x over previous
//
#include <hip/hip_runtime.h>
#include <cmath>

#define NN 100000
#define NE 1600000
#define NG 512
#define H 200
#define D 205
#define EPSV 1e-5f
#define SCAN_B 1024
#define KP 224    // weight (B-side) k-pitch, bf16, zero-padded
#define LPH 208   // node-buffer k-pitch (elements)

typedef __attribute__((ext_vector_type(8))) short short8v;
typedef __attribute__((ext_vector_type(4))) float f32x4;

#define MFMA16(a,b,c) __builtin_amdgcn_mfma_f32_16x16x32_bf16(a,b,c,0,0,0)

static __device__ __forceinline__ float sigm(float x){ return 1.0f/(1.0f+expf(-x)); }

// split fp32 -> bf16 hi (truncate) + bf16 lo (residual)
static __device__ __forceinline__ void split2(float x, unsigned short& h, unsigned short& l){
  unsigned xb = __float_as_uint(x);
  h = (unsigned short)(xb >> 16);
  float hf = __uint_as_float(xb & 0xffff0000u);
  l = (unsigned short)(__float_as_uint(x - hf) >> 16);
}

static __device__ __forceinline__ float uf(unsigned short u){
  return __uint_as_float(((unsigned)u) << 16);
}

static __device__ __forceinline__ void gload16(const void* src, void* dst){
  __builtin_amdgcn_global_load_lds(
      (const __attribute__((address_space(1))) unsigned int*)src,
      (__attribute__((address_space(3))) unsigned int*)dst, 16, 0, 0);
}

// ---------------- cvt fp32 [rows,C] -> hi/lo bf16 [rows,P], zero-padded ----------------
__global__ __launch_bounds__(256) void cvt_split(const float* __restrict__ in,
    unsigned short* __restrict__ hi, unsigned short* __restrict__ lo, int rows, int C, int P){
  long i = (long)blockIdx.x*256 + threadIdx.x;
  long tot = (long)rows*P;
  if (i >= tot) return;
  int r = (int)(i/P), c = (int)(i - (long)r*P);
  float v = (c < C) ? in[(size_t)r*C + c] : 0.f;
  unsigned short hh, ll; split2(v,hh,ll);
  hi[i] = hh; lo[i] = ll;
}

// ---------------- cvt + transpose: out[n][k]=in[k][n], [C,KP], zero-padded ----------------
__global__ __launch_bounds__(256) void cvt_tsplit(const float* __restrict__ in,
    unsigned short* __restrict__ hi, unsigned short* __restrict__ lo, int R, int C){
  int i = blockIdx.x*256 + threadIdx.x;
  if (i >= C*KP) return;
  int n = i/KP, k = i - n*KP;
  float v = (k < R) ? in[(size_t)k*C + n] : 0.f;
  unsigned short hh, ll; split2(v,hh,ll);
  hi[i] = hh; lo[i] = ll;
}

// ---------------- split-bf16 MFMA GEMM: C = (Ahi+Alo) @ (Bhi+Blo)^T, 3-term ----------------
// A direct global->VGPR; B staged in LDS. EPIL=1: bias+BN+ReLU -> split pair (pads zeroed).
// EPIL=0: raw fp32 out (m, gather-only; fp32 pads never read).
template<int EPIL>
__global__ __launch_bounds__(256) void mgemm(
    const unsigned short* __restrict__ Ahi, const unsigned short* __restrict__ Alo,
    const unsigned short* __restrict__ Bhi, const unsigned short* __restrict__ Blo,
    int M, int N, int nj, int npan,
    const float* __restrict__ bias,
    const float* __restrict__ bg, const float* __restrict__ bb,
    const float* __restrict__ bm, const float* __restrict__ bv,
    unsigned short* __restrict__ Chi, unsigned short* __restrict__ Clo,
    float* __restrict__ Cf)
{
  __shared__ __align__(16) char S[16384];   // Bhi 0..8K, Blo 8K..16K (granule-major)
  const int bid = blockIdx.x;
  const int xcd = bid & 7, sl = bid >> 3;
  const int pl = sl / nj, jj = sl - pl*nj;
  const int p = pl*8 + xcd;
  if (p >= npan) return;
  const int n0 = jj*128, r0 = p*128;
  const int tid = threadIdx.x, lane = tid & 63, wave = tid >> 6;
  const int wr = (wave>>1)*64, wc = (wave&1)*64;
  const int fr = lane & 15, fq = lane >> 4;
  f32x4 acc[4][4] = {};

  const unsigned short* sp[4]; int sdst[4];
  #pragma unroll
  for (int i = 0; i < 4; ++i) {
    int g = wave + 4*i;                 // 0..15
    int region = g >> 3, c = g & 7, rowgrp = c >> 2, q = c & 3;
    int row = rowgrp*64 + lane;
    int rg = n0 + row; if (rg > N-1) rg = N-1;
    sp[i] = (region ? Blo : Bhi) + (size_t)rg*KP + q*8;
    sdst[i] = region*8192 + q*2048 + rowgrp*1024;
  }
  int arow[4];
  #pragma unroll
  for (int t = 0; t < 4; ++t) {
    int rg = r0 + wr + t*16 + fr; if (rg > M-1) rg = M-1;
    arow[t] = rg*LPH + fq*8;
  }

  for (int k0 = 0; k0 < KP; k0 += 32) {
    #pragma unroll
    for (int i = 0; i < 4; ++i) gload16(sp[i] + k0, S + sdst[i]);
    __syncthreads();
    short8v ah[4], al[4], bh[4], bl[4];
    #pragma unroll
    for (int t = 0; t < 4; ++t) {
      ah[t] = *(const short8v*)(Ahi + arow[t] + k0);
      al[t] = *(const short8v*)(Alo + arow[t] + k0);
      int rb = (wc + t*16 + fr)*16;
      bh[t] = *(const short8v*)(S +    0 + fq*2048 + rb);
      bl[t] = *(const short8v*)(S + 8192 + fq*2048 + rb);
    }
    #pragma unroll
    for (int i = 0; i < 4; ++i)
      #pragma unroll
      for (int j = 0; j < 4; ++j) {
        acc[i][j] = MFMA16(ah[i], bh[j], acc[i][j]);
        acc[i][j] = MFMA16(ah[i], bl[j], acc[i][j]);
        acc[i][j] = MFMA16(al[i], bh[j], acc[i][j]);
      }
    __syncthreads();
  }

  #pragma unroll
  for (int i = 0; i < 4; ++i)
    #pragma unroll
    for (int j = 0; j < 4; ++j)
      #pragma unroll
      for (int q = 0; q < 4; ++q) {
        int row = r0 + wr + i*16 + fq*4 + q;
        int col = n0 + wc + j*16 + fr;
        if (row < M && col < N) {
          float c = acc[i][j][q];
          if (EPIL) {
            c += bias[col];
            c = (c - bm[col]) * (bg[col] * rsqrtf(bv[col] + EPSV)) + bb[col];
            c = fmaxf(c, 0.f);
            unsigned short hh, ll; split2(c, hh, ll);
            size_t o = (size_t)row*LPH + col;
            Chi[o] = hh; Clo[o] = ll;
          } else {
            Cf[(size_t)row*LPH + col] = c;
          }
        } else if (EPIL && row < M && col >= N && col < LPH) {
          // zero pad cols so downstream A-overreads (k in [200,208)) stay finite
          size_t o = (size_t)row*LPH + col;
          Chi[o] = 0; Clo[o] = 0;
        }
      }
}

// ---------------- fused GRU: 4-acc form, LDS W staging (round-12 proven) ----------------
// Output pads [H,LPH) zeroed: the pair region previously held fp32 m bytes, which as
// bf16 patterns can be NaN/Inf -> next mgemm A-overread would poison the MFMA.
__global__ __launch_bounds__(256, 3) void gru6(
    const unsigned short* __restrict__ Ghi, const unsigned short* __restrict__ Glo,
    const unsigned short* __restrict__ Hhi, const unsigned short* __restrict__ Hlo,
    const unsigned short* __restrict__ Wihh, const unsigned short* __restrict__ Wihl,
    const unsigned short* __restrict__ Whhh, const unsigned short* __restrict__ Whhl,
    const float* __restrict__ bih, const float* __restrict__ bhh,
    int nj, int npan,
    unsigned short* __restrict__ Ohi, unsigned short* __restrict__ Olo)
{
  __shared__ __align__(16) char S[24576];   // Ws0 0..12K, Ws1 12K..24K (granule-major)
  const int bid = blockIdx.x;
  const int xcd = bid & 7, sl = bid >> 3;
  const int pl = sl / nj, jt = sl - pl*nj;
  const int p = pl*8 + xcd;
  if (p >= npan) return;
  const int j0 = jt*32, r0 = p*128;
  const int tid = threadIdx.x, lane = tid & 63, wave = tid >> 6;
  const int fr = lane & 15, fq = lane >> 4;
  f32x4 acc[4][2][2] = {};   // [0]=r(i+h), [1]=z(i+h), [2]=n-in, [3]=n-hid

  const unsigned short* sp[6]; int sdst[6];
  #pragma unroll
  for (int i = 0; i < 6; ++i) {
    int g = wave + 4*i;                 // 0..23
    int comp = g / 12, c = g - comp*12, rowgrp = c >> 2, q = c & 3;
    int R = rowgrp*64 + lane, gate = R>>5, jjj = R&31;
    int g3 = (gate >= 3) ? gate-3 : gate;
    int jcol = j0 + jjj; if (jcol > H-1) jcol = H-1;
    const unsigned short* base = (gate < 3) ? (comp ? Wihl : Wihh) : (comp ? Whhl : Whhh);
    sp[i] = base + (size_t)(g3*H + jcol)*KP + q*8;
    sdst[i] = comp*12288 + q*3072 + rowgrp*1024;
  }
  int arow[2];
  #pragma unroll
  for (int t = 0; t < 2; ++t) {
    int rg = r0 + wave*32 + t*16 + fr; if (rg > NN-1) rg = NN-1;
    arow[t] = rg*LPH + fq*8;
  }

  for (int k0 = 0; k0 < KP; k0 += 32) {
    #pragma unroll
    for (int i = 0; i < 6; ++i) gload16(sp[i] + k0, S + sdst[i]);
    __syncthreads();
    short8v A[4][2];   // [comp: g-hi, g-lo, h-hi, h-lo][t]
    #pragma unroll
    for (int t = 0; t < 2; ++t) {
      A[0][t] = *(const short8v*)(Ghi + arow[t] + k0);
      A[1][t] = *(const short8v*)(Glo + arow[t] + k0);
      A[2][t] = *(const short8v*)(Hhi + arow[t] + k0);
      A[3][t] = *(const short8v*)(Hlo + arow[t] + k0);
    }
    #pragma unroll
    for (int g = 0; g < 6; ++g) {
      const char* w0 = S +     0 + fq*3072;
      const char* w1 = S + 12288 + fq*3072;
      short8v b0h = *(const short8v*)(w0 + (g*32      + fr)*16);
      short8v b1h = *(const short8v*)(w0 + (g*32 + 16 + fr)*16);
      short8v b0l = *(const short8v*)(w1 + (g*32      + fr)*16);
      short8v b1l = *(const short8v*)(w1 + (g*32 + 16 + fr)*16);
      const int ai = (g < 3) ? 0 : 2;               // input path vs hidden path
      const int ac = (g == 5) ? 3 : (g % 3);        // r,z shared; n-in=2, n-hid=3
      #pragma unroll
      for (int t = 0; t < 2; ++t) {
        acc[ac][t][0] = MFMA16(A[ai][t],   b0h, acc[ac][t][0]);
        acc[ac][t][0] = MFMA16(A[ai][t],   b0l, acc[ac][t][0]);
        acc[ac][t][0] = MFMA16(A[ai+1][t], b0h, acc[ac][t][0]);
        acc[ac][t][1] = MFMA16(A[ai][t],   b1h, acc[ac][t][1]);
        acc[ac][t][1] = MFMA16(A[ai][t],   b1l, acc[ac][t][1]);
        acc[ac][t][1] = MFMA16(A[ai+1][t], b1h, acc[ac][t][1]);
      }
    }
    __syncthreads();
  }

  #pragma unroll
  for (int ct = 0; ct < 2; ++ct) {
    int j = j0 + ct*16 + fr;
    if (j >= LPH) continue;
    if (j >= H) {
      // zero the pad columns (kills fp32-m residue -> keeps A-overreads finite)
      #pragma unroll
      for (int t = 0; t < 2; ++t)
        #pragma unroll
        for (int q = 0; q < 4; ++q) {
          int row = r0 + wave*32 + t*16 + fq*4 + q;
          if (row >= NN) continue;
          size_t o = (size_t)row*LPH + j;
          Ohi[o] = 0; Olo[o] = 0;
        }
      continue;
    }
    float br  = bih[j]     + bhh[j];
    float bz  = bih[H+j]   + bhh[H+j];
    float bin = bih[2*H+j], bhn = bhh[2*H+j];
    #pragma unroll
    for (int t = 0; t < 2; ++t)
      #pragma unroll
      for (int q = 0; q < 4; ++q) {
        int row = r0 + wave*32 + t*16 + fq*4 + q;
        if (row >= NN) continue;
        float rv = sigm(acc[0][t][ct][q] + br);
        float zv = sigm(acc[1][t][ct][q] + bz);
        float nv = tanhf(acc[2][t][ct][q] + bin + rv*(acc[3][t][ct][q] + bhn));
        size_t o = (size_t)row*LPH + j;
        float ho = uf(Hhi[o]) + uf(Hlo[o]);
        unsigned short hh2, ll2; split2((1.f - zv)*nv + zv*ho, hh2, ll2);
        Ohi[o] = hh2; Olo[o] = ll2;
      }
  }
}

// ---------------- CSR build ----------------
__global__ __launch_bounds__(256) void hist_k(const int* __restrict__ dst, int* __restrict__ deg){
  int e = blockIdx.x*256 + threadIdx.x;
  if (e < NE) atomicAdd(&deg[dst[e]], 1);
}

__global__ __launch_bounds__(256) void scan1_k(const int* __restrict__ deg, int* __restrict__ part,
                                               int* __restrict__ bsum, int n){
  __shared__ int lds[256];
  int t = threadIdx.x;
  int base = blockIdx.x * SCAN_B + t*4;
  int v[4]; int s = 0;
  #pragma unroll
  for (int q = 0; q < 4; ++q){ int idx = base+q; v[q] = (idx < n) ? deg[idx] : 0; s += v[q]; }
  lds[t] = s;
  __syncthreads();
  for (int off = 1; off < 256; off <<= 1){
    int val = 0;
    if (t >= off) val = lds[t-off];
    __syncthreads();
    if (t >= off) lds[t] += val;
    __syncthreads();
  }
  if (t == 255) bsum[blockIdx.x] = lds[255];
  int run = (t == 0) ? 0 : lds[t-1];
  #pragma unroll
  for (int q = 0; q < 4; ++q){ int idx = base+q; if (idx < n) part[idx] = run; run += v[q]; }
}

__global__ void scan2_k(int* __restrict__ bsum, int nb){
  __shared__ int lds[128];
  int t = threadIdx.x;
  int v = (t < nb) ? bsum[t] : 0;
  lds[t] = v;
  __syncthreads();
  for (int off = 1; off < 128; off <<= 1){
    int val = 0;
    if (t >= off) val = lds[t-off];
    __syncthreads();
    if (t >= off) lds[t] += val;
    __syncthreads();
  }
  if (t < nb) bsum[t] = (t == 0) ? 0 : lds[t-1];
}

__global__ __launch_bounds__(256) void scan3_k(const int* __restrict__ part, const int* __restrict__ bsum,
                                               int* __restrict__ rowptr, int* __restrict__ cpos, int n){
  int i = blockIdx.x*256 + threadIdx.x;
  if (i < n){
    int v = part[i] + bsum[i >> 10];
    rowptr[i] = v;
    cpos[i] = v;
  }
  if (i == 0) rowptr[n] = NE;
}

__global__ __launch_bounds__(256) void fill_k(const int* __restrict__ src, const int* __restrict__ dst,
                                              int* __restrict__ cpos, int* __restrict__ elist){
  int e = blockIdx.x*256 + threadIdx.x;
  if (e < NE){
    int p = atomicAdd(&cpos[dst[e]], 1);
    elist[p] = src[e];
  }
}

// ---------------- gather: agg[n] = sum m[src] (fp32); sIdx preload + 4-way ILP ----------------
__global__ __launch_bounds__(256) void gather_k(const float* __restrict__ m,
                                                const int* __restrict__ rowptr,
                                                const int* __restrict__ elist,
                                                unsigned short* __restrict__ ahi,
                                                unsigned short* __restrict__ alo){
  __shared__ int sIdx[256];
  int n = blockIdx.x;
  int beg = rowptr[n], end = rowptr[n+1];
  int j = threadIdx.x;
  float a0=0.f, a1=0.f, a2=0.f, a3=0.f;
  for (int c0 = beg; c0 < end; c0 += 256){
    int cnt = min(256, end - c0);
    __syncthreads();
    if (threadIdx.x < cnt) sIdx[threadIdx.x] = elist[c0 + threadIdx.x];
    __syncthreads();
    if (j < H){
      int k = 0;
      for (; k + 4 <= cnt; k += 4){
        a0 += m[(size_t)sIdx[k  ]*LPH + j];
        a1 += m[(size_t)sIdx[k+1]*LPH + j];
        a2 += m[(size_t)sIdx[k+2]*LPH + j];
        a3 += m[(size_t)sIdx[k+3]*LPH + j];
      }
      for (; k < cnt; ++k){
        a0 += m[(size_t)sIdx[k]*LPH + j];
      }
    }
  }
  if (j < H){
    unsigned short hh, ll; split2((a0 + a1) + (a2 + a3), hh, ll);
    size_t o = (size_t)n*LPH + j;
    ahi[o] = hh; alo[o] = ll;
  }
}

// ---------------- pooling: one block per graph (batch sorted) ----------------
__global__ __launch_bounds__(256) void pool_g(
    const unsigned short* __restrict__ hhi, const unsigned short* __restrict__ hlo,
    const int* __restrict__ batch,
    const float* __restrict__ g2, const float* __restrict__ b2,
    const float* __restrict__ m2, const float* __restrict__ v2,
    float* __restrict__ gmean, float* __restrict__ gmax)
{
  int g = blockIdx.x;
  int lo = 0, hi = NN;
  while (lo < hi){ int mid = (lo+hi)>>1; if (batch[mid] < g) lo = mid+1; else hi = mid; }
  int lo2 = lo, hi2 = NN;
  while (lo2 < hi2){ int mid = (lo2+hi2)>>1; if (batch[mid] < g+1) lo2 = mid+1; else hi2 = mid; }
  int j = threadIdx.x;
  if (j >= H) return;
  float s = g2[j] * rsqrtf(v2[j] + EPSV);
  float mm = m2[j], bb = b2[j];
  float sum = 0.f, mx = 0.f;
  for (int n = lo; n < hi2; ++n){
    size_t o = (size_t)n*LPH + j;
    float hv = uf(hhi[o]) + uf(hlo[o]);
    float val = fmaxf((hv - mm)*s + bb, 0.f);
    sum += val;
    mx = fmaxf(mx, val);
  }
  int c = hi2 - lo;
  gmean[g*H + j] = (c > 0) ? sum/(float)c : 0.f;
  gmax [g*H + j] = mx;
}

// ---------------- fc1 + bnf + relu ----------------
__global__ __launch_bounds__(256) void fc1_k(
    const float* __restrict__ gmean, const float* __restrict__ gmax,
    const float* __restrict__ W,
    const float* __restrict__ bias,
    const float* __restrict__ fg, const float* __restrict__ fb,
    const float* __restrict__ fm, const float* __restrict__ fv,
    float* __restrict__ out)
{
  int tid = blockIdx.x*256 + threadIdx.x;
  if (tid >= NG*H) return;
  int g = tid / H, j = tid - g*H;
  const float* wr = W + j*2*H;
  float acc = bias[j];
  for (int k = 0; k < H; ++k) acc += gmean[g*H + k] * wr[k];
  for (int k = 0; k < H; ++k) acc += gmax[g*H + k] * wr[H + k];
  float s = fg[j] * rsqrtf(fv[j] + EPSV);
  acc = (acc - fm[j]) * s + fb[j];
  out[tid] = fmaxf(acc, 0.f);
}

__global__ void fc2_k(const float* __restrict__ in, const float* __restrict__ W,
                      const float* __restrict__ bias, float* __restrict__ out)
{
  int tid = blockIdx.x*256 + threadIdx.x;
  if (tid >= NG*2) return;
  int g = tid >> 1, c = tid & 1;
  float acc = bias[c];
  const float* wr = W + c*H;
  const float* xr = in + g*H;
  for (int k = 0; k < H; ++k) acc += xr[k]*wr[k];
  out[tid] = acc;
}

extern "C" void kernel_launch(void* const* d_in, const int* in_sizes, int n_in,
                              void* d_out, int out_size, void* d_ws, size_t ws_size,
                              hipStream_t stream)
{
  const float* x     = (const float*)d_in[0];
  const int*   eidx  = (const int*)d_in[1];
  const int*   batch = (const int*)d_in[2];
  const float* projW = (const float*)d_in[3];
  const float* projb = (const float*)d_in[4];
  const float* bn1g  = (const float*)d_in[5];
  const float* bn1b  = (const float*)d_in[6];
  const float* bn1m  = (const float*)d_in[7];
  const float* bn1v  = (const float*)d_in[8];
  const float* bn2g  = (const float*)d_in[9];
  const float* bn2b  = (const float*)d_in[10];
  const float* bn2m  = (const float*)d_in[11];
  const float* bn2v  = (const float*)d_in[12];
  const float* bnfg  = (const float*)d_in[13];
  const float* bnfb  = (const float*)d_in[14];
  const float* bnfm  = (const float*)d_in[15];
  const float* bnfv  = (const float*)d_in[16];
  const float* ggcW  = (const float*)d_in[17];
  const float* wih   = (const float*)d_in[18];
  const float* whh   = (const float*)d_in[19];
  const float* bih   = (const float*)d_in[20];
  const float* bhh   = (const float*)d_in[21];
  const float* fc1W  = (const float*)d_in[22];
  const float* fc1b  = (const float*)d_in[23];
  const float* fc2W  = (const float*)d_in[24];
  const float* fc2b  = (const float*)d_in[25];

  char* wsp = (char*)d_ws;
  auto alloc = [&](size_t nbytes) {
    char* p = wsp;
    wsp += ((nbytes + 255) / 256) * 256;
    return (void*)p;
  };
  // Node tensors: three PAIR-REGIONS (hi half + lo half contiguous, 83.2MB each) with a
  // 256B zeroed guard after each (A-overreads of the last row land in the guard, not in
  // possibly-NaN-patterned fp32 data).
  const size_t PAIRE = (size_t)NN*LPH;            // elements per half
  unsigned short* xaHi = (unsigned short*)alloc(PAIRE*4);
  unsigned short* xaLo = xaHi + PAIRE;
  char* grd0 = (char*)alloc(256);
  unsigned short* hHi  = (unsigned short*)alloc(PAIRE*4);
  unsigned short* hLo  = hHi + PAIRE;
  char* grd1 = (char*)alloc(256);
  unsigned short* mHi  = (unsigned short*)alloc(PAIRE*4);
  unsigned short* mLo  = mHi + PAIRE;
  char* grd2 = (char*)alloc(256);
  // weights (bf16 split, zero-padded to KP)
  unsigned short* pBh   = (unsigned short*)alloc((size_t)H*KP*2);
  unsigned short* pBl   = (unsigned short*)alloc((size_t)H*KP*2);
  unsigned short* wihBh = (unsigned short*)alloc((size_t)3*H*KP*2);
  unsigned short* wihBl = (unsigned short*)alloc((size_t)3*H*KP*2);
  unsigned short* whhBh = (unsigned short*)alloc((size_t)3*H*KP*2);
  unsigned short* whhBl = (unsigned short*)alloc((size_t)3*H*KP*2);
  unsigned short* gBh[3]; unsigned short* gBl[3];
  for (int i = 0; i < 3; ++i) {
    gBh[i] = (unsigned short*)alloc((size_t)H*KP*2);
    gBl[i] = (unsigned short*)alloc((size_t)H*KP*2);
  }
  float* gmean = (float*)alloc((size_t)NG*H*4);
  float* gmax  = (float*)alloc((size_t)NG*H*4);
  float* fc1o  = (float*)alloc((size_t)NG*H*4);
  const int NB = (NN + SCAN_B - 1) / SCAN_B;
  int* deg    = (int*)alloc((size_t)NN*4);
  int* part   = (int*)alloc((size_t)NN*4);
  int* bsum   = (int*)alloc((size_t)NB*4);
  int* rowptr = (int*)alloc((size_t)(NN+1)*4);
  int* cpos   = (int*)alloc((size_t)NN*4);
  int* elist  = (int*)alloc((size_t)NE*4);

  const int* srcp = eidx;
  const int* dstp = eidx + NE;

  // zero the guards (overread landing zones)
  hipMemsetAsync(grd0, 0, 256, stream);
  hipMemsetAsync(grd1, 0, 256, stream);
  hipMemsetAsync(grd2, 0, 256, stream);

  // ---- CSR build (reused all 3 steps) ----
  hipMemsetAsync(deg, 0, (size_t)NN*4, stream);
  hist_k<<<(NE + 255)/256, 256, 0, stream>>>(dstp, deg);
  scan1_k<<<NB, 256, 0, stream>>>(deg, part, bsum, NN);
  scan2_k<<<1, 128, 0, stream>>>(bsum, NB);
  scan3_k<<<(NN + 255)/256, 256, 0, stream>>>(part, bsum, rowptr, cpos, NN);
  fill_k<<<(NE + 255)/256, 256, 0, stream>>>(srcp, dstp, cpos, elist);

  // ---- weight splits (pitch KP, zero-padded) ----
  cvt_split<<<(int)(((long)H*KP + 255)/256), 256, 0, stream>>>(projW, pBh, pBl, H, D, KP);
  cvt_split<<<(int)(((long)3*H*KP + 255)/256), 256, 0, stream>>>(wih, wihBh, wihBl, 3*H, H, KP);
  cvt_split<<<(int)(((long)3*H*KP + 255)/256), 256, 0, stream>>>(whh, whhBh, whhBl, 3*H, H, KP);
  for (int i = 0; i < 3; ++i)
    cvt_tsplit<<<(H*KP + 255)/256, 256, 0, stream>>>(ggcW + (size_t)i*H*H, gBh[i], gBl[i], H, H);

  // ---- x -> split pair (pitch LPH, zero-padded pads) ----
  cvt_split<<<(int)(((long)NN*LPH + 255)/256), 256, 0, stream>>>(x, xaHi, xaLo, NN, D, LPH);

  // XCD-grouped grids
  const int NPAN = (NN + 127)/128;            // 782
  const int PL8  = (NPAN + 7)/8;              // 98
  const int NJ_G = (H + 127)/128;             // 2
  const int NJ_U = (H + 31)/32;               // 7
  const int GRID_G = 8 * NJ_G * PL8;
  const int GRID_U = 8 * NJ_U * PL8;

  // proj + bn1 + relu : xpair -> hpair (pads zeroed by epilogue)
  mgemm<1><<<GRID_G, 256, 0, stream>>>(xaHi, xaLo, pBh, pBl, NN, H, NJ_G, NPAN,
                                       projb, bn1g, bn1b, bn1m, bn1v, hHi, hLo, nullptr);

  unsigned short *chHi = hHi, *chLo = hLo, *cmHi = mHi, *cmLo = mLo;
  for (int i = 0; i < 3; ++i) {
    float* mF = (float*)cmHi;   // fp32 view over the contiguous cm pair-region
    mgemm<0><<<GRID_G, 256, 0, stream>>>(chHi, chLo, gBh[i], gBl[i], NN, H, NJ_G, NPAN,
                                         nullptr, nullptr, nullptr, nullptr, nullptr,
                                         nullptr, nullptr, mF);
    gather_k<<<NN, 256, 0, stream>>>(mF, rowptr, elist, xaHi, xaLo);
    gru6<<<GRID_U, 256, 0, stream>>>(xaHi, xaLo, chHi, chLo,
                                     wihBh, wihBl, whhBh, whhBl,
                                     bih, bhh, NJ_U, NPAN, cmHi, cmLo);
    unsigned short* t;
    t = chHi; chHi = cmHi; cmHi = t;
    t = chLo; chLo = cmLo; cmLo = t;
  }

  pool_g<<<NG, 256, 0, stream>>>(chHi, chLo, batch, bn2g, bn2b, bn2m, bn2v, gmean, gmax);
  fc1_k<<<(NG*H + 255)/256, 256, 0, stream>>>(gmean, gmax, fc1W, fc1b,
                                              bnfg, bnfb, bnfm, bnfv, fc1o);
  fc2_k<<<(NG*2 + 255)/256, 256, 0, stream>>>(fc1o, fc2W, fc2b, (float*)d_out);
}

// Round 16
// 1960.782 us; speedup vs baseline: 1.2485x; 1.0821x over previous
//
#include <hip/hip_runtime.h>
#include <cmath>

#define NN 100000
#define NE 1600000
#define NG 512
#define H 200
#define D 205
#define EPSV 1e-5f
#define SCAN_B 1024
#define KP 224    // weight (B-side) k-pitch, bf16, zero-padded
#define LPH 208   // node-buffer k-pitch (elements)

typedef __attribute__((ext_vector_type(8))) short short8v;
typedef __attribute__((ext_vector_type(4))) float f32x4;

#define MFMA16(a,b,c) __builtin_amdgcn_mfma_f32_16x16x32_bf16(a,b,c,0,0,0)

static __device__ __forceinline__ float sigm(float x){ return 1.0f/(1.0f+expf(-x)); }

// split fp32 -> bf16 hi (truncate) + bf16 lo (residual)
static __device__ __forceinline__ void split2(float x, unsigned short& h, unsigned short& l){
  unsigned xb = __float_as_uint(x);
  h = (unsigned short)(xb >> 16);
  float hf = __uint_as_float(xb & 0xffff0000u);
  l = (unsigned short)(__float_as_uint(x - hf) >> 16);
}

static __device__ __forceinline__ float uf(unsigned short u){
  return __uint_as_float(((unsigned)u) << 16);
}

static __device__ __forceinline__ void gload16(const void* src, void* dst){
  __builtin_amdgcn_global_load_lds(
      (const __attribute__((address_space(1))) unsigned int*)src,
      (__attribute__((address_space(3))) unsigned int*)dst, 16, 0, 0);
}

// ---------------- cvt fp32 [rows,C] -> hi/lo bf16 [rows,P], zero-padded ----------------
__global__ __launch_bounds__(256) void cvt_split(const float* __restrict__ in,
    unsigned short* __restrict__ hi, unsigned short* __restrict__ lo, int rows, int C, int P){
  long i = (long)blockIdx.x*256 + threadIdx.x;
  long tot = (long)rows*P;
  if (i >= tot) return;
  int r = (int)(i/P), c = (int)(i - (long)r*P);
  float v = (c < C) ? in[(size_t)r*C + c] : 0.f;
  unsigned short hh, ll; split2(v,hh,ll);
  hi[i] = hh; lo[i] = ll;
}

// ---------------- cvt + transpose: out[n][k]=in[k][n], [C,KP], zero-padded ----------------
__global__ __launch_bounds__(256) void cvt_tsplit(const float* __restrict__ in,
    unsigned short* __restrict__ hi, unsigned short* __restrict__ lo, int R, int C){
  int i = blockIdx.x*256 + threadIdx.x;
  if (i >= C*KP) return;
  int n = i/KP, k = i - n*KP;
  float v = (k < R) ? in[(size_t)k*C + n] : 0.f;
  unsigned short hh, ll; split2(v,hh,ll);
  hi[i] = hh; lo[i] = ll;
}

// ---------------- split-bf16 MFMA GEMM, single-barrier double-buffered pipeline -------
// Canonical §5 pattern: per iter {stage(k+1)->buf^1; prefetch A(k+1)->regs; MFMA(k);
// one __syncthreads}. Barrier drain overlaps MFMA. A direct global->VGPR; B in LDS.
template<int EPIL>
__global__ __launch_bounds__(256) void mgemm(
    const unsigned short* __restrict__ Ahi, const unsigned short* __restrict__ Alo,
    const unsigned short* __restrict__ Bhi, const unsigned short* __restrict__ Blo,
    int M, int N, int nj, int npan,
    const float* __restrict__ bias,
    const float* __restrict__ bg, const float* __restrict__ bb,
    const float* __restrict__ bm, const float* __restrict__ bv,
    unsigned short* __restrict__ Chi, unsigned short* __restrict__ Clo,
    float* __restrict__ Cf)
{
  __shared__ __align__(16) char S[2][16384];   // per buf: Bhi 0..8K, Blo 8K..16K
  const int bid = blockIdx.x;
  const int xcd = bid & 7, sl = bid >> 3;
  const int pl = sl / nj, jj = sl - pl*nj;
  const int p = pl*8 + xcd;
  if (p >= npan) return;
  const int n0 = jj*128, r0 = p*128;
  const int tid = threadIdx.x, lane = tid & 63, wave = tid >> 6;
  const int wr = (wave>>1)*64, wc = (wave&1)*64;
  const int fr = lane & 15, fq = lane >> 4;
  f32x4 acc[4][4] = {};

  const unsigned short* sp[4]; int sdst[4];
  #pragma unroll
  for (int i = 0; i < 4; ++i) {
    int g = wave + 4*i;                 // 0..15
    int region = g >> 3, c = g & 7, rowgrp = c >> 2, q = c & 3;
    int row = rowgrp*64 + lane;
    int rg = n0 + row; if (rg > N-1) rg = N-1;
    sp[i] = (region ? Blo : Bhi) + (size_t)rg*KP + q*8;
    sdst[i] = region*8192 + q*2048 + rowgrp*1024;
  }
  int arow[4];
  #pragma unroll
  for (int t = 0; t < 4; ++t) {
    int rg = r0 + wr + t*16 + fr; if (rg > M-1) rg = M-1;
    arow[t] = rg*LPH + fq*8;
  }

  short8v AH[4], AL[4], NH[4], NL[4];
  // prologue: stage k0=0 and load A(0); barrier drains both
  #pragma unroll
  for (int i = 0; i < 4; ++i) gload16(sp[i], S[0] + sdst[i]);
  #pragma unroll
  for (int t = 0; t < 4; ++t) {
    AH[t] = *(const short8v*)(Ahi + arow[t]);
    AL[t] = *(const short8v*)(Alo + arow[t]);
  }
  __syncthreads();

  for (int kk = 0; kk < 7; ++kk) {
    const int kb = kk & 1;
    if (kk < 6) {
      const int kn = (kk+1)*32;
      #pragma unroll
      for (int i = 0; i < 4; ++i) gload16(sp[i] + kn, S[kb^1] + sdst[i]);
      #pragma unroll
      for (int t = 0; t < 4; ++t) {
        NH[t] = *(const short8v*)(Ahi + arow[t] + kn);
        NL[t] = *(const short8v*)(Alo + arow[t] + kn);
      }
    }
    short8v bh[4], bl[4];
    #pragma unroll
    for (int t = 0; t < 4; ++t) {
      int rb = (wc + t*16 + fr)*16;
      bh[t] = *(const short8v*)(S[kb] +    0 + fq*2048 + rb);
      bl[t] = *(const short8v*)(S[kb] + 8192 + fq*2048 + rb);
    }
    #pragma unroll
    for (int i = 0; i < 4; ++i)
      #pragma unroll
      for (int j = 0; j < 4; ++j) {
        acc[i][j] = MFMA16(AH[i], bh[j], acc[i][j]);
        acc[i][j] = MFMA16(AH[i], bl[j], acc[i][j]);
        acc[i][j] = MFMA16(AL[i], bh[j], acc[i][j]);
      }
    __syncthreads();   // drains stage(k+1)+loadA(k+1); overlapped with MFMAs above
    if (kk < 6) {
      #pragma unroll
      for (int t = 0; t < 4; ++t) { AH[t] = NH[t]; AL[t] = NL[t]; }
    }
  }

  #pragma unroll
  for (int i = 0; i < 4; ++i)
    #pragma unroll
    for (int j = 0; j < 4; ++j)
      #pragma unroll
      for (int q = 0; q < 4; ++q) {
        int row = r0 + wr + i*16 + fq*4 + q;
        int col = n0 + wc + j*16 + fr;
        if (row < M && col < N) {
          float c = acc[i][j][q];
          if (EPIL) {
            c += bias[col];
            c = (c - bm[col]) * (bg[col] * rsqrtf(bv[col] + EPSV)) + bb[col];
            c = fmaxf(c, 0.f);
            unsigned short hh, ll; split2(c, hh, ll);
            size_t o = (size_t)row*LPH + col;
            Chi[o] = hh; Clo[o] = ll;
          } else {
            Cf[(size_t)row*LPH + col] = c;
          }
        } else if (EPIL && row < M && col >= N && col < LPH) {
          size_t o = (size_t)row*LPH + col;
          Chi[o] = 0; Clo[o] = 0;
        }
      }
}

// ---------------- fused GRU: 4-acc, single-barrier double-buffered pipeline -----------
__global__ __launch_bounds__(256, 2) void gru6(
    const unsigned short* __restrict__ Ghi, const unsigned short* __restrict__ Glo,
    const unsigned short* __restrict__ Hhi, const unsigned short* __restrict__ Hlo,
    const unsigned short* __restrict__ Wihh, const unsigned short* __restrict__ Wihl,
    const unsigned short* __restrict__ Whhh, const unsigned short* __restrict__ Whhl,
    const float* __restrict__ bih, const float* __restrict__ bhh,
    int nj, int npan,
    unsigned short* __restrict__ Ohi, unsigned short* __restrict__ Olo)
{
  __shared__ __align__(16) char S[2][24576];   // per buf: Ws0 0..12K, Ws1 12K..24K
  const int bid = blockIdx.x;
  const int xcd = bid & 7, sl = bid >> 3;
  const int pl = sl / nj, jt = sl - pl*nj;
  const int p = pl*8 + xcd;
  if (p >= npan) return;
  const int j0 = jt*32, r0 = p*128;
  const int tid = threadIdx.x, lane = tid & 63, wave = tid >> 6;
  const int fr = lane & 15, fq = lane >> 4;
  f32x4 acc[4][2][2] = {};   // [0]=r(i+h), [1]=z(i+h), [2]=n-in, [3]=n-hid

  const unsigned short* sp[6]; int sdst[6];
  #pragma unroll
  for (int i = 0; i < 6; ++i) {
    int g = wave + 4*i;                 // 0..23
    int comp = g / 12, c = g - comp*12, rowgrp = c >> 2, q = c & 3;
    int R = rowgrp*64 + lane, gate = R>>5, jjj = R&31;
    int g3 = (gate >= 3) ? gate-3 : gate;
    int jcol = j0 + jjj; if (jcol > H-1) jcol = H-1;
    const unsigned short* base = (gate < 3) ? (comp ? Wihl : Wihh) : (comp ? Whhl : Whhh);
    sp[i] = base + (size_t)(g3*H + jcol)*KP + q*8;
    sdst[i] = comp*12288 + q*3072 + rowgrp*1024;
  }
  int arow[2];
  #pragma unroll
  for (int t = 0; t < 2; ++t) {
    int rg = r0 + wave*32 + t*16 + fr; if (rg > NN-1) rg = NN-1;
    arow[t] = rg*LPH + fq*8;
  }

  short8v Ac[4][2], An[4][2];   // [comp: g-hi, g-lo, h-hi, h-lo][t]
  // prologue
  #pragma unroll
  for (int i = 0; i < 6; ++i) gload16(sp[i], S[0] + sdst[i]);
  #pragma unroll
  for (int t = 0; t < 2; ++t) {
    Ac[0][t] = *(const short8v*)(Ghi + arow[t]);
    Ac[1][t] = *(const short8v*)(Glo + arow[t]);
    Ac[2][t] = *(const short8v*)(Hhi + arow[t]);
    Ac[3][t] = *(const short8v*)(Hlo + arow[t]);
  }
  __syncthreads();

  for (int kk = 0; kk < 7; ++kk) {
    const int kb = kk & 1;
    if (kk < 6) {
      const int kn = (kk+1)*32;
      #pragma unroll
      for (int i = 0; i < 6; ++i) gload16(sp[i] + kn, S[kb^1] + sdst[i]);
      #pragma unroll
      for (int t = 0; t < 2; ++t) {
        An[0][t] = *(const short8v*)(Ghi + arow[t] + kn);
        An[1][t] = *(const short8v*)(Glo + arow[t] + kn);
        An[2][t] = *(const short8v*)(Hhi + arow[t] + kn);
        An[3][t] = *(const short8v*)(Hlo + arow[t] + kn);
      }
    }
    const char* w0 = S[kb] +     0 + fq*3072;
    const char* w1 = S[kb] + 12288 + fq*3072;
    #pragma unroll
    for (int g = 0; g < 6; ++g) {
      short8v b0h = *(const short8v*)(w0 + (g*32      + fr)*16);
      short8v b1h = *(const short8v*)(w0 + (g*32 + 16 + fr)*16);
      short8v b0l = *(const short8v*)(w1 + (g*32      + fr)*16);
      short8v b1l = *(const short8v*)(w1 + (g*32 + 16 + fr)*16);
      const int ai = (g < 3) ? 0 : 2;               // input path vs hidden path
      const int ac = (g == 5) ? 3 : (g % 3);        // r,z shared; n-in=2, n-hid=3
      #pragma unroll
      for (int t = 0; t < 2; ++t) {
        acc[ac][t][0] = MFMA16(Ac[ai][t],   b0h, acc[ac][t][0]);
        acc[ac][t][0] = MFMA16(Ac[ai][t],   b0l, acc[ac][t][0]);
        acc[ac][t][0] = MFMA16(Ac[ai+1][t], b0h, acc[ac][t][0]);
        acc[ac][t][1] = MFMA16(Ac[ai][t],   b1h, acc[ac][t][1]);
        acc[ac][t][1] = MFMA16(Ac[ai][t],   b1l, acc[ac][t][1]);
        acc[ac][t][1] = MFMA16(Ac[ai+1][t], b1h, acc[ac][t][1]);
      }
    }
    __syncthreads();   // drains stage(k+1)+loadA(k+1); overlapped with MFMAs above
    if (kk < 6) {
      #pragma unroll
      for (int c2 = 0; c2 < 4; ++c2)
        #pragma unroll
        for (int t = 0; t < 2; ++t) Ac[c2][t] = An[c2][t];
    }
  }

  #pragma unroll
  for (int ct = 0; ct < 2; ++ct) {
    int j = j0 + ct*16 + fr;
    if (j >= LPH) continue;
    if (j >= H) {
      #pragma unroll
      for (int t = 0; t < 2; ++t)
        #pragma unroll
        for (int q = 0; q < 4; ++q) {
          int row = r0 + wave*32 + t*16 + fq*4 + q;
          if (row >= NN) continue;
          size_t o = (size_t)row*LPH + j;
          Ohi[o] = 0; Olo[o] = 0;
        }
      continue;
    }
    float br  = bih[j]     + bhh[j];
    float bz  = bih[H+j]   + bhh[H+j];
    float bin = bih[2*H+j], bhn = bhh[2*H+j];
    #pragma unroll
    for (int t = 0; t < 2; ++t)
      #pragma unroll
      for (int q = 0; q < 4; ++q) {
        int row = r0 + wave*32 + t*16 + fq*4 + q;
        if (row >= NN) continue;
        float rv = sigm(acc[0][t][ct][q] + br);
        float zv = sigm(acc[1][t][ct][q] + bz);
        float nv = tanhf(acc[2][t][ct][q] + bin + rv*(acc[3][t][ct][q] + bhn));
        size_t o = (size_t)row*LPH + j;
        float ho = uf(Hhi[o]) + uf(Hlo[o]);
        unsigned short hh2, ll2; split2((1.f - zv)*nv + zv*ho, hh2, ll2);
        Ohi[o] = hh2; Olo[o] = ll2;
      }
  }
}

// ---------------- CSR build ----------------
__global__ __launch_bounds__(256) void hist_k(const int* __restrict__ dst, int* __restrict__ deg){
  int e = blockIdx.x*256 + threadIdx.x;
  if (e < NE) atomicAdd(&deg[dst[e]], 1);
}

__global__ __launch_bounds__(256) void scan1_k(const int* __restrict__ deg, int* __restrict__ part,
                                               int* __restrict__ bsum, int n){
  __shared__ int lds[256];
  int t = threadIdx.x;
  int base = blockIdx.x * SCAN_B + t*4;
  int v[4]; int s = 0;
  #pragma unroll
  for (int q = 0; q < 4; ++q){ int idx = base+q; v[q] = (idx < n) ? deg[idx] : 0; s += v[q]; }
  lds[t] = s;
  __syncthreads();
  for (int off = 1; off < 256; off <<= 1){
    int val = 0;
    if (t >= off) val = lds[t-off];
    __syncthreads();
    if (t >= off) lds[t] += val;
    __syncthreads();
  }
  if (t == 255) bsum[blockIdx.x] = lds[255];
  int run = (t == 0) ? 0 : lds[t-1];
  #pragma unroll
  for (int q = 0; q < 4; ++q){ int idx = base+q; if (idx < n) part[idx] = run; run += v[q]; }
}

__global__ void scan2_k(int* __restrict__ bsum, int nb){
  __shared__ int lds[128];
  int t = threadIdx.x;
  int v = (t < nb) ? bsum[t] : 0;
  lds[t] = v;
  __syncthreads();
  for (int off = 1; off < 128; off <<= 1){
    int val = 0;
    if (t >= off) val = lds[t-off];
    __syncthreads();
    if (t >= off) lds[t] += val;
    __syncthreads();
  }
  if (t < nb) bsum[t] = (t == 0) ? 0 : lds[t-1];
}

__global__ __launch_bounds__(256) void scan3_k(const int* __restrict__ part, const int* __restrict__ bsum,
                                               int* __restrict__ rowptr, int* __restrict__ cpos, int n){
  int i = blockIdx.x*256 + threadIdx.x;
  if (i < n){
    int v = part[i] + bsum[i >> 10];
    rowptr[i] = v;
    cpos[i] = v;
  }
  if (i == 0) rowptr[n] = NE;
}

__global__ __launch_bounds__(256) void fill_k(const int* __restrict__ src, const int* __restrict__ dst,
                                              int* __restrict__ cpos, int* __restrict__ elist){
  int e = blockIdx.x*256 + threadIdx.x;
  if (e < NE){
    int p = atomicAdd(&cpos[dst[e]], 1);
    elist[p] = src[e];
  }
}

// ---------------- gather: agg[n] = sum m[src] (fp32); sIdx preload + 4-way ILP ----------------
__global__ __launch_bounds__(256) void gather_k(const float* __restrict__ m,
                                                const int* __restrict__ rowptr,
                                                const int* __restrict__ elist,
                                                unsigned short* __restrict__ ahi,
                                                unsigned short* __restrict__ alo){
  __shared__ int sIdx[256];
  int n = blockIdx.x;
  int beg = rowptr[n], end = rowptr[n+1];
  int j = threadIdx.x;
  float a0=0.f, a1=0.f, a2=0.f, a3=0.f;
  for (int c0 = beg; c0 < end; c0 += 256){
    int cnt = min(256, end - c0);
    __syncthreads();
    if (threadIdx.x < cnt) sIdx[threadIdx.x] = elist[c0 + threadIdx.x];
    __syncthreads();
    if (j < H){
      int k = 0;
      for (; k + 4 <= cnt; k += 4){
        a0 += m[(size_t)sIdx[k  ]*LPH + j];
        a1 += m[(size_t)sIdx[k+1]*LPH + j];
        a2 += m[(size_t)sIdx[k+2]*LPH + j];
        a3 += m[(size_t)sIdx[k+3]*LPH + j];
      }
      for (; k < cnt; ++k){
        a0 += m[(size_t)sIdx[k]*LPH + j];
      }
    }
  }
  if (j < H){
    unsigned short hh, ll; split2((a0 + a1) + (a2 + a3), hh, ll);
    size_t o = (size_t)n*LPH + j;
    ahi[o] = hh; alo[o] = ll;
  }
}

// ---------------- pooling: one block per graph (batch sorted) ----------------
__global__ __launch_bounds__(256) void pool_g(
    const unsigned short* __restrict__ hhi, const unsigned short* __restrict__ hlo,
    const int* __restrict__ batch,
    const float* __restrict__ g2, const float* __restrict__ b2,
    const float* __restrict__ m2, const float* __restrict__ v2,
    float* __restrict__ gmean, float* __restrict__ gmax)
{
  int g = blockIdx.x;
  int lo = 0, hi = NN;
  while (lo < hi){ int mid = (lo+hi)>>1; if (batch[mid] < g) lo = mid+1; else hi = mid; }
  int lo2 = lo, hi2 = NN;
  while (lo2 < hi2){ int mid = (lo2+hi2)>>1; if (batch[mid] < g+1) lo2 = mid+1; else hi2 = mid; }
  int j = threadIdx.x;
  if (j >= H) return;
  float s = g2[j] * rsqrtf(v2[j] + EPSV);
  float mm = m2[j], bb = b2[j];
  float sum = 0.f, mx = 0.f;
  for (int n = lo; n < hi2; ++n){
    size_t o = (size_t)n*LPH + j;
    float hv = uf(hhi[o]) + uf(hlo[o]);
    float val = fmaxf((hv - mm)*s + bb, 0.f);
    sum += val;
    mx = fmaxf(mx, val);
  }
  int c = hi2 - lo;
  gmean[g*H + j] = (c > 0) ? sum/(float)c : 0.f;
  gmax [g*H + j] = mx;
}

// ---------------- fc1 + bnf + relu ----------------
__global__ __launch_bounds__(256) void fc1_k(
    const float* __restrict__ gmean, const float* __restrict__ gmax,
    const float* __restrict__ W,
    const float* __restrict__ bias,
    const float* __restrict__ fg, const float* __restrict__ fb,
    const float* __restrict__ fm, const float* __restrict__ fv,
    float* __restrict__ out)
{
  int tid = blockIdx.x*256 + threadIdx.x;
  if (tid >= NG*H) return;
  int g = tid / H, j = tid - g*H;
  const float* wr = W + j*2*H;
  float acc = bias[j];
  for (int k = 0; k < H; ++k) acc += gmean[g*H + k] * wr[k];
  for (int k = 0; k < H; ++k) acc += gmax[g*H + k] * wr[H + k];
  float s = fg[j] * rsqrtf(fv[j] + EPSV);
  acc = (acc - fm[j]) * s + fb[j];
  out[tid] = fmaxf(acc, 0.f);
}

__global__ void fc2_k(const float* __restrict__ in, const float* __restrict__ W,
                      const float* __restrict__ bias, float* __restrict__ out)
{
  int tid = blockIdx.x*256 + threadIdx.x;
  if (tid >= NG*2) return;
  int g = tid >> 1, c = tid & 1;
  float acc = bias[c];
  const float* wr = W + c*H;
  const float* xr = in + g*H;
  for (int k = 0; k < H; ++k) acc += xr[k]*wr[k];
  out[tid] = acc;
}

extern "C" void kernel_launch(void* const* d_in, const int* in_sizes, int n_in,
                              void* d_out, int out_size, void* d_ws, size_t ws_size,
                              hipStream_t stream)
{
  const float* x     = (const float*)d_in[0];
  const int*   eidx  = (const int*)d_in[1];
  const int*   batch = (const int*)d_in[2];
  const float* projW = (const float*)d_in[3];
  const float* projb = (const float*)d_in[4];
  const float* bn1g  = (const float*)d_in[5];
  const float* bn1b  = (const float*)d_in[6];
  const float* bn1m  = (const float*)d_in[7];
  const float* bn1v  = (const float*)d_in[8];
  const float* bn2g  = (const float*)d_in[9];
  const float* bn2b  = (const float*)d_in[10];
  const float* bn2m  = (const float*)d_in[11];
  const float* bn2v  = (const float*)d_in[12];
  const float* bnfg  = (const float*)d_in[13];
  const float* bnfb  = (const float*)d_in[14];
  const float* bnfm  = (const float*)d_in[15];
  const float* bnfv  = (const float*)d_in[16];
  const float* ggcW  = (const float*)d_in[17];
  const float* wih   = (const float*)d_in[18];
  const float* whh   = (const float*)d_in[19];
  const float* bih   = (const float*)d_in[20];
  const float* bhh   = (const float*)d_in[21];
  const float* fc1W  = (const float*)d_in[22];
  const float* fc1b  = (const float*)d_in[23];
  const float* fc2W  = (const float*)d_in[24];
  const float* fc2b  = (const float*)d_in[25];

  char* wsp = (char*)d_ws;
  auto alloc = [&](size_t nbytes) {
    char* p = wsp;
    wsp += ((nbytes + 255) / 256) * 256;
    return (void*)p;
  };
  // Node tensors: three pair-regions (hi+lo contiguous) with zeroed 256B guards.
  const size_t PAIRE = (size_t)NN*LPH;            // elements per half
  unsigned short* xaHi = (unsigned short*)alloc(PAIRE*4);
  unsigned short* xaLo = xaHi + PAIRE;
  char* grd0 = (char*)alloc(256);
  unsigned short* hHi  = (unsigned short*)alloc(PAIRE*4);
  unsigned short* hLo  = hHi + PAIRE;
  char* grd1 = (char*)alloc(256);
  unsigned short* mHi  = (unsigned short*)alloc(PAIRE*4);
  unsigned short* mLo  = mHi + PAIRE;
  char* grd2 = (char*)alloc(256);
  // weights (bf16 split, zero-padded to KP)
  unsigned short* pBh   = (unsigned short*)alloc((size_t)H*KP*2);
  unsigned short* pBl   = (unsigned short*)alloc((size_t)H*KP*2);
  unsigned short* wihBh = (unsigned short*)alloc((size_t)3*H*KP*2);
  unsigned short* wihBl = (unsigned short*)alloc((size_t)3*H*KP*2);
  unsigned short* whhBh = (unsigned short*)alloc((size_t)3*H*KP*2);
  unsigned short* whhBl = (unsigned short*)alloc((size_t)3*H*KP*2);
  unsigned short* gBh[3]; unsigned short* gBl[3];
  for (int i = 0; i < 3; ++i) {
    gBh[i] = (unsigned short*)alloc((size_t)H*KP*2);
    gBl[i] = (unsigned short*)alloc((size_t)H*KP*2);
  }
  float* gmean = (float*)alloc((size_t)NG*H*4);
  float* gmax  = (float*)alloc((size_t)NG*H*4);
  float* fc1o  = (float*)alloc((size_t)NG*H*4);
  const int NB = (NN + SCAN_B - 1) / SCAN_B;
  int* deg    = (int*)alloc((size_t)NN*4);
  int* part   = (int*)alloc((size_t)NN*4);
  int* bsum   = (int*)alloc((size_t)NB*4);
  int* rowptr = (int*)alloc((size_t)(NN+1)*4);
  int* cpos   = (int*)alloc((size_t)NN*4);
  int* elist  = (int*)alloc((size_t)NE*4);

  const int* srcp = eidx;
  const int* dstp = eidx + NE;

  // zero the guards (overread landing zones)
  hipMemsetAsync(grd0, 0, 256, stream);
  hipMemsetAsync(grd1, 0, 256, stream);
  hipMemsetAsync(grd2, 0, 256, stream);

  // ---- CSR build (reused all 3 steps) ----
  hipMemsetAsync(deg, 0, (size_t)NN*4, stream);
  hist_k<<<(NE + 255)/256, 256, 0, stream>>>(dstp, deg);
  scan1_k<<<NB, 256, 0, stream>>>(deg, part, bsum, NN);
  scan2_k<<<1, 128, 0, stream>>>(bsum, NB);
  scan3_k<<<(NN + 255)/256, 256, 0, stream>>>(part, bsum, rowptr, cpos, NN);
  fill_k<<<(NE + 255)/256, 256, 0, stream>>>(srcp, dstp, cpos, elist);

  // ---- weight splits (pitch KP, zero-padded) ----
  cvt_split<<<(int)(((long)H*KP + 255)/256), 256, 0, stream>>>(projW, pBh, pBl, H, D, KP);
  cvt_split<<<(int)(((long)3*H*KP + 255)/256), 256, 0, stream>>>(wih, wihBh, wihBl, 3*H, H, KP);
  cvt_split<<<(int)(((long)3*H*KP + 255)/256), 256, 0, stream>>>(whh, whhBh, whhBl, 3*H, H, KP);
  for (int i = 0; i < 3; ++i)
    cvt_tsplit<<<(H*KP + 255)/256, 256, 0, stream>>>(ggcW + (size_t)i*H*H, gBh[i], gBl[i], H, H);

  // ---- x -> split pair (pitch LPH, zero-padded pads) ----
  cvt_split<<<(int)(((long)NN*LPH + 255)/256), 256, 0, stream>>>(x, xaHi, xaLo, NN, D, LPH);

  // XCD-grouped grids
  const int NPAN = (NN + 127)/128;            // 782
  const int PL8  = (NPAN + 7)/8;              // 98
  const int NJ_G = (H + 127)/128;             // 2
  const int NJ_U = (H + 31)/32;               // 7
  const int GRID_G = 8 * NJ_G * PL8;
  const int GRID_U = 8 * NJ_U * PL8;

  // proj + bn1 + relu : xpair -> hpair (pads zeroed by epilogue)
  mgemm<1><<<GRID_G, 256, 0, stream>>>(xaHi, xaLo, pBh, pBl, NN, H, NJ_G, NPAN,
                                       projb, bn1g, bn1b, bn1m, bn1v, hHi, hLo, nullptr);

  unsigned short *chHi = hHi, *chLo = hLo, *cmHi = mHi, *cmLo = mLo;
  for (int i = 0; i < 3; ++i) {
    float* mF = (float*)cmHi;   // fp32 view over the contiguous cm pair-region
    mgemm<0><<<GRID_G, 256, 0, stream>>>(chHi, chLo, gBh[i], gBl[i], NN, H, NJ_G, NPAN,
                                         nullptr, nullptr, nullptr, nullptr, nullptr,
                                         nullptr, nullptr, mF);
    gather_k<<<NN, 256, 0, stream>>>(mF, rowptr, elist, xaHi, xaLo);
    gru6<<<GRID_U, 256, 0, stream>>>(xaHi, xaLo, chHi, chLo,
                                     wihBh, wihBl, whhBh, whhBl,
                                     bih, bhh, NJ_U, NPAN, cmHi, cmLo);
    unsigned short* t;
    t = chHi; chHi = cmHi; cmHi = t;
    t = chLo; chLo = cmLo; cmLo = t;
  }

  pool_g<<<NG, 256, 0, stream>>>(chHi, chLo, batch, bn2g, bn2b, bn2m, bn2v, gmean, gmax);
  fc1_k<<<(NG*H + 255)/256, 256, 0, stream>>>(gmean, gmax, fc1W, fc1b,
                                              bnfg, bnfb, bnfm, bnfv, fc1o);
  fc2_k<<<(NG*2 + 255)/256, 256, 0, stream>>>(fc1o, fc2W, fc2b, (float*)d_out);
}

// Round 17
// 1919.351 us; speedup vs baseline: 1.2755x; 1.0216x over previous
//
#include <hip/hip_runtime.h>
#include <cmath>

#define NN 100000
#define NE 1600000
#define NG 512
#define H 200
#define D 205
#define EPSV 1e-5f
#define SCAN_B 1024
#define KP 224    // weight k-pitch, bf16, zero-padded
#define LPH 208   // node-buffer k-pitch (elements)

typedef __attribute__((ext_vector_type(8))) short short8v;
typedef __attribute__((ext_vector_type(4))) float f32x4;

#define MFMA16(a,b,c) __builtin_amdgcn_mfma_f32_16x16x32_bf16(a,b,c,0,0,0)

static __device__ __forceinline__ float sigm(float x){ return 1.0f/(1.0f+expf(-x)); }

// split fp32 -> bf16 hi (truncate) + bf16 lo (residual)
static __device__ __forceinline__ void split2(float x, unsigned short& h, unsigned short& l){
  unsigned xb = __float_as_uint(x);
  h = (unsigned short)(xb >> 16);
  float hf = __uint_as_float(xb & 0xffff0000u);
  l = (unsigned short)(__float_as_uint(x - hf) >> 16);
}

static __device__ __forceinline__ float uf(unsigned short u){
  return __uint_as_float(((unsigned)u) << 16);
}

static __device__ __forceinline__ void gload16(const void* src, void* dst){
  __builtin_amdgcn_global_load_lds(
      (const __attribute__((address_space(1))) unsigned int*)src,
      (__attribute__((address_space(3))) unsigned int*)dst, 16, 0, 0);
}

// ---------------- cvt fp32 [rows,C] -> hi/lo bf16 [rows,P], zero-padded ----------------
__global__ __launch_bounds__(256) void cvt_split(const float* __restrict__ in,
    unsigned short* __restrict__ hi, unsigned short* __restrict__ lo, int rows, int C, int P){
  long i = (long)blockIdx.x*256 + threadIdx.x;
  long tot = (long)rows*P;
  if (i >= tot) return;
  int r = (int)(i/P), c = (int)(i - (long)r*P);
  float v = (c < C) ? in[(size_t)r*C + c] : 0.f;
  unsigned short hh, ll; split2(v,hh,ll);
  hi[i] = hh; lo[i] = ll;
}

// ---------------- split-bf16 MFMA GEMM, single-barrier double-buffered pipeline -------
// C[M,N] = (Ahi+Alo) @ (Bhi+Blo)^T, 3-term. A pitch LPA; B pitch KP.
// EPIL=1: bias+BN+ReLU -> split pair out (pitch LPH, pads zeroed).
// EPIL=0: raw fp32 out, pitch LPC.
template<int EPIL>
__global__ __launch_bounds__(256) void mgemm(
    const unsigned short* __restrict__ Ahi, const unsigned short* __restrict__ Alo,
    const unsigned short* __restrict__ Bhi, const unsigned short* __restrict__ Blo,
    int M, int N, int nj, int npan, int LPA, int LPC,
    const float* __restrict__ bias,
    const float* __restrict__ bg, const float* __restrict__ bb,
    const float* __restrict__ bm, const float* __restrict__ bv,
    unsigned short* __restrict__ Chi, unsigned short* __restrict__ Clo,
    float* __restrict__ Cf)
{
  __shared__ __align__(16) char S[2][16384];   // per buf: Bhi 0..8K, Blo 8K..16K
  const int bid = blockIdx.x;
  const int xcd = bid & 7, sl = bid >> 3;
  const int pl = sl / nj, jj = sl - pl*nj;
  const int p = pl*8 + xcd;
  if (p >= npan) return;
  const int n0 = jj*128, r0 = p*128;
  const int tid = threadIdx.x, lane = tid & 63, wave = tid >> 6;
  const int wr = (wave>>1)*64, wc = (wave&1)*64;
  const int fr = lane & 15, fq = lane >> 4;
  f32x4 acc[4][4] = {};

  const unsigned short* sp[4]; int sdst[4];
  #pragma unroll
  for (int i = 0; i < 4; ++i) {
    int g = wave + 4*i;                 // 0..15
    int region = g >> 3, c = g & 7, rowgrp = c >> 2, q = c & 3;
    int row = rowgrp*64 + lane;
    int rg = n0 + row; if (rg > N-1) rg = N-1;
    sp[i] = (region ? Blo : Bhi) + (size_t)rg*KP + q*8;
    sdst[i] = region*8192 + q*2048 + rowgrp*1024;
  }
  int arow[4];
  #pragma unroll
  for (int t = 0; t < 4; ++t) {
    int rg = r0 + wr + t*16 + fr; if (rg > M-1) rg = M-1;
    arow[t] = rg*LPA + fq*8;
  }

  short8v AH[4], AL[4], NH[4], NL[4];
  #pragma unroll
  for (int i = 0; i < 4; ++i) gload16(sp[i], S[0] + sdst[i]);
  #pragma unroll
  for (int t = 0; t < 4; ++t) {
    AH[t] = *(const short8v*)(Ahi + arow[t]);
    AL[t] = *(const short8v*)(Alo + arow[t]);
  }
  __syncthreads();

  for (int kk = 0; kk < 7; ++kk) {
    const int kb = kk & 1;
    if (kk < 6) {
      const int kn = (kk+1)*32;
      #pragma unroll
      for (int i = 0; i < 4; ++i) gload16(sp[i] + kn, S[kb^1] + sdst[i]);
      #pragma unroll
      for (int t = 0; t < 4; ++t) {
        NH[t] = *(const short8v*)(Ahi + arow[t] + kn);
        NL[t] = *(const short8v*)(Alo + arow[t] + kn);
      }
    }
    short8v bh[4], bl[4];
    #pragma unroll
    for (int t = 0; t < 4; ++t) {
      int rb = (wc + t*16 + fr)*16;
      bh[t] = *(const short8v*)(S[kb] +    0 + fq*2048 + rb);
      bl[t] = *(const short8v*)(S[kb] + 8192 + fq*2048 + rb);
    }
    #pragma unroll
    for (int i = 0; i < 4; ++i)
      #pragma unroll
      for (int j = 0; j < 4; ++j) {
        acc[i][j] = MFMA16(AH[i], bh[j], acc[i][j]);
        acc[i][j] = MFMA16(AH[i], bl[j], acc[i][j]);
        acc[i][j] = MFMA16(AL[i], bh[j], acc[i][j]);
      }
    __syncthreads();
    if (kk < 6) {
      #pragma unroll
      for (int t = 0; t < 4; ++t) { AH[t] = NH[t]; AL[t] = NL[t]; }
    }
  }

  #pragma unroll
  for (int i = 0; i < 4; ++i)
    #pragma unroll
    for (int j = 0; j < 4; ++j)
      #pragma unroll
      for (int q = 0; q < 4; ++q) {
        int row = r0 + wr + i*16 + fq*4 + q;
        int col = n0 + wc + j*16 + fr;
        if (row < M && col < N) {
          float c = acc[i][j][q];
          if (EPIL) {
            c += bias[col];
            c = (c - bm[col]) * (bg[col] * rsqrtf(bv[col] + EPSV)) + bb[col];
            c = fmaxf(c, 0.f);
            unsigned short hh, ll; split2(c, hh, ll);
            size_t o = (size_t)row*LPH + col;
            Chi[o] = hh; Clo[o] = ll;
          } else {
            Cf[(size_t)row*LPC + col] = c;
          }
        } else if (EPIL && row < M && col >= N && col < LPH) {
          size_t o = (size_t)row*LPH + col;
          Chi[o] = 0; Clo[o] = 0;
        }
      }
}

// ---------------- fused GRU: 4-acc, single-barrier double-buffered pipeline -----------
__global__ __launch_bounds__(256, 2) void gru6(
    const unsigned short* __restrict__ Ghi, const unsigned short* __restrict__ Glo,
    const unsigned short* __restrict__ Hhi, const unsigned short* __restrict__ Hlo,
    const unsigned short* __restrict__ Wihh, const unsigned short* __restrict__ Wihl,
    const unsigned short* __restrict__ Whhh, const unsigned short* __restrict__ Whhl,
    const float* __restrict__ bih, const float* __restrict__ bhh,
    int nj, int npan,
    unsigned short* __restrict__ Ohi, unsigned short* __restrict__ Olo)
{
  __shared__ __align__(16) char S[2][24576];   // per buf: Ws0 0..12K, Ws1 12K..24K
  const int bid = blockIdx.x;
  const int xcd = bid & 7, sl = bid >> 3;
  const int pl = sl / nj, jt = sl - pl*nj;
  const int p = pl*8 + xcd;
  if (p >= npan) return;
  const int j0 = jt*32, r0 = p*128;
  const int tid = threadIdx.x, lane = tid & 63, wave = tid >> 6;
  const int fr = lane & 15, fq = lane >> 4;
  f32x4 acc[4][2][2] = {};   // [0]=r(i+h), [1]=z(i+h), [2]=n-in, [3]=n-hid

  const unsigned short* sp[6]; int sdst[6];
  #pragma unroll
  for (int i = 0; i < 6; ++i) {
    int g = wave + 4*i;                 // 0..23
    int comp = g / 12, c = g - comp*12, rowgrp = c >> 2, q = c & 3;
    int R = rowgrp*64 + lane, gate = R>>5, jjj = R&31;
    int g3 = (gate >= 3) ? gate-3 : gate;
    int jcol = j0 + jjj; if (jcol > H-1) jcol = H-1;
    const unsigned short* base = (gate < 3) ? (comp ? Wihl : Wihh) : (comp ? Whhl : Whhh);
    sp[i] = base + (size_t)(g3*H + jcol)*KP + q*8;
    sdst[i] = comp*12288 + q*3072 + rowgrp*1024;
  }
  int arow[2];
  #pragma unroll
  for (int t = 0; t < 2; ++t) {
    int rg = r0 + wave*32 + t*16 + fr; if (rg > NN-1) rg = NN-1;
    arow[t] = rg*LPH + fq*8;
  }

  short8v Ac[4][2], An[4][2];   // [comp: g-hi, g-lo, h-hi, h-lo][t]
  #pragma unroll
  for (int i = 0; i < 6; ++i) gload16(sp[i], S[0] + sdst[i]);
  #pragma unroll
  for (int t = 0; t < 2; ++t) {
    Ac[0][t] = *(const short8v*)(Ghi + arow[t]);
    Ac[1][t] = *(const short8v*)(Glo + arow[t]);
    Ac[2][t] = *(const short8v*)(Hhi + arow[t]);
    Ac[3][t] = *(const short8v*)(Hlo + arow[t]);
  }
  __syncthreads();

  for (int kk = 0; kk < 7; ++kk) {
    const int kb = kk & 1;
    if (kk < 6) {
      const int kn = (kk+1)*32;
      #pragma unroll
      for (int i = 0; i < 6; ++i) gload16(sp[i] + kn, S[kb^1] + sdst[i]);
      #pragma unroll
      for (int t = 0; t < 2; ++t) {
        An[0][t] = *(const short8v*)(Ghi + arow[t] + kn);
        An[1][t] = *(const short8v*)(Glo + arow[t] + kn);
        An[2][t] = *(const short8v*)(Hhi + arow[t] + kn);
        An[3][t] = *(const short8v*)(Hlo + arow[t] + kn);
      }
    }
    const char* w0 = S[kb] +     0 + fq*3072;
    const char* w1 = S[kb] + 12288 + fq*3072;
    #pragma unroll
    for (int g = 0; g < 6; ++g) {
      short8v b0h = *(const short8v*)(w0 + (g*32      + fr)*16);
      short8v b1h = *(const short8v*)(w0 + (g*32 + 16 + fr)*16);
      short8v b0l = *(const short8v*)(w1 + (g*32      + fr)*16);
      short8v b1l = *(const short8v*)(w1 + (g*32 + 16 + fr)*16);
      const int ai = (g < 3) ? 0 : 2;               // input path vs hidden path
      const int ac = (g == 5) ? 3 : (g % 3);        // r,z shared; n-in=2, n-hid=3
      #pragma unroll
      for (int t = 0; t < 2; ++t) {
        acc[ac][t][0] = MFMA16(Ac[ai][t],   b0h, acc[ac][t][0]);
        acc[ac][t][0] = MFMA16(Ac[ai][t],   b0l, acc[ac][t][0]);
        acc[ac][t][0] = MFMA16(Ac[ai+1][t], b0h, acc[ac][t][0]);
        acc[ac][t][1] = MFMA16(Ac[ai][t],   b1h, acc[ac][t][1]);
        acc[ac][t][1] = MFMA16(Ac[ai][t],   b1l, acc[ac][t][1]);
        acc[ac][t][1] = MFMA16(Ac[ai+1][t], b1h, acc[ac][t][1]);
      }
    }
    __syncthreads();
    if (kk < 6) {
      #pragma unroll
      for (int c2 = 0; c2 < 4; ++c2)
        #pragma unroll
        for (int t = 0; t < 2; ++t) Ac[c2][t] = An[c2][t];
    }
  }

  #pragma unroll
  for (int ct = 0; ct < 2; ++ct) {
    int j = j0 + ct*16 + fr;
    if (j >= LPH) continue;
    if (j >= H) {
      #pragma unroll
      for (int t = 0; t < 2; ++t)
        #pragma unroll
        for (int q = 0; q < 4; ++q) {
          int row = r0 + wave*32 + t*16 + fq*4 + q;
          if (row >= NN) continue;
          size_t o = (size_t)row*LPH + j;
          Ohi[o] = 0; Olo[o] = 0;
        }
      continue;
    }
    float br  = bih[j]     + bhh[j];
    float bz  = bih[H+j]   + bhh[H+j];
    float bin = bih[2*H+j], bhn = bhh[2*H+j];
    #pragma unroll
    for (int t = 0; t < 2; ++t)
      #pragma unroll
      for (int q = 0; q < 4; ++q) {
        int row = r0 + wave*32 + t*16 + fq*4 + q;
        if (row >= NN) continue;
        float rv = sigm(acc[0][t][ct][q] + br);
        float zv = sigm(acc[1][t][ct][q] + bz);
        float nv = tanhf(acc[2][t][ct][q] + bin + rv*(acc[3][t][ct][q] + bhn));
        size_t o = (size_t)row*LPH + j;
        float ho = uf(Hhi[o]) + uf(Hlo[o]);
        unsigned short hh2, ll2; split2((1.f - zv)*nv + zv*ho, hh2, ll2);
        Ohi[o] = hh2; Olo[o] = ll2;
      }
  }
}

// ---------------- CSR build ----------------
__global__ __launch_bounds__(256) void hist_k(const int* __restrict__ dst, int* __restrict__ deg){
  int e = blockIdx.x*256 + threadIdx.x;
  if (e < NE) atomicAdd(&deg[dst[e]], 1);
}

__global__ __launch_bounds__(256) void scan1_k(const int* __restrict__ deg, int* __restrict__ part,
                                               int* __restrict__ bsum, int n){
  __shared__ int lds[256];
  int t = threadIdx.x;
  int base = blockIdx.x * SCAN_B + t*4;
  int v[4]; int s = 0;
  #pragma unroll
  for (int q = 0; q < 4; ++q){ int idx = base+q; v[q] = (idx < n) ? deg[idx] : 0; s += v[q]; }
  lds[t] = s;
  __syncthreads();
  for (int off = 1; off < 256; off <<= 1){
    int val = 0;
    if (t >= off) val = lds[t-off];
    __syncthreads();
    if (t >= off) lds[t] += val;
    __syncthreads();
  }
  if (t == 255) bsum[blockIdx.x] = lds[255];
  int run = (t == 0) ? 0 : lds[t-1];
  #pragma unroll
  for (int q = 0; q < 4; ++q){ int idx = base+q; if (idx < n) part[idx] = run; run += v[q]; }
}

__global__ void scan2_k(int* __restrict__ bsum, int nb){
  __shared__ int lds[128];
  int t = threadIdx.x;
  int v = (t < nb) ? bsum[t] : 0;
  lds[t] = v;
  __syncthreads();
  for (int off = 1; off < 128; off <<= 1){
    int val = 0;
    if (t >= off) val = lds[t-off];
    __syncthreads();
    if (t >= off) lds[t] += val;
    __syncthreads();
  }
  if (t < nb) bsum[t] = (t == 0) ? 0 : lds[t-1];
}

__global__ __launch_bounds__(256) void scan3_k(const int* __restrict__ part, const int* __restrict__ bsum,
                                               int* __restrict__ rowptr, int* __restrict__ cpos, int n){
  int i = blockIdx.x*256 + threadIdx.x;
  if (i < n){
    int v = part[i] + bsum[i >> 10];
    rowptr[i] = v;
    cpos[i] = v;
  }
  if (i == 0) rowptr[n] = NE;
}

__global__ __launch_bounds__(256) void fill_k(const int* __restrict__ src, const int* __restrict__ dst,
                                              int* __restrict__ cpos, int* __restrict__ elist){
  int e = blockIdx.x*256 + threadIdx.x;
  if (e < NE){
    int p = atomicAdd(&cpos[dst[e]], 1);
    elist[p] = src[e];
  }
}

// ---------------- gather: hg[n] = sum h[src] (bf16 pair in/out); sIdx + 4-way ILP -----
__global__ __launch_bounds__(256) void gather_k(const unsigned short* __restrict__ mhi,
                                                const unsigned short* __restrict__ mlo,
                                                const int* __restrict__ rowptr,
                                                const int* __restrict__ elist,
                                                unsigned short* __restrict__ ahi,
                                                unsigned short* __restrict__ alo){
  __shared__ int sIdx[256];
  int n = blockIdx.x;
  int beg = rowptr[n], end = rowptr[n+1];
  int j = threadIdx.x;
  float a0=0.f, a1=0.f, a2=0.f, a3=0.f;
  for (int c0 = beg; c0 < end; c0 += 256){
    int cnt = min(256, end - c0);
    __syncthreads();
    if (threadIdx.x < cnt) sIdx[threadIdx.x] = elist[c0 + threadIdx.x];
    __syncthreads();
    if (j < H){
      int k = 0;
      for (; k + 4 <= cnt; k += 4){
        size_t s0 = (size_t)sIdx[k  ]*LPH + j;
        size_t s1 = (size_t)sIdx[k+1]*LPH + j;
        size_t s2 = (size_t)sIdx[k+2]*LPH + j;
        size_t s3 = (size_t)sIdx[k+3]*LPH + j;
        a0 += uf(mhi[s0]) + uf(mlo[s0]);
        a1 += uf(mhi[s1]) + uf(mlo[s1]);
        a2 += uf(mhi[s2]) + uf(mlo[s2]);
        a3 += uf(mhi[s3]) + uf(mlo[s3]);
      }
      for (; k < cnt; ++k){
        size_t s = (size_t)sIdx[k]*LPH + j;
        a0 += uf(mhi[s]) + uf(mlo[s]);
      }
    }
  }
  if (j < H){
    unsigned short hh, ll; split2((a0 + a1) + (a2 + a3), hh, ll);
    size_t o = (size_t)n*LPH + j;
    ahi[o] = hh; alo[o] = ll;
  }
}

// ---------------- pooling: one block per graph (batch sorted) ----------------
__global__ __launch_bounds__(256) void pool_g(
    const unsigned short* __restrict__ hhi, const unsigned short* __restrict__ hlo,
    const int* __restrict__ batch,
    const float* __restrict__ g2, const float* __restrict__ b2,
    const float* __restrict__ m2, const float* __restrict__ v2,
    float* __restrict__ gmean, float* __restrict__ gmax)
{
  int g = blockIdx.x;
  int lo = 0, hi = NN;
  while (lo < hi){ int mid = (lo+hi)>>1; if (batch[mid] < g) lo = mid+1; else hi = mid; }
  int lo2 = lo, hi2 = NN;
  while (lo2 < hi2){ int mid = (lo2+hi2)>>1; if (batch[mid] < g+1) lo2 = mid+1; else hi2 = mid; }
  int j = threadIdx.x;
  if (j >= H) return;
  float s = g2[j] * rsqrtf(v2[j] + EPSV);
  float mm = m2[j], bb = b2[j];
  float sum = 0.f, mx = 0.f;
  for (int n = lo; n < hi2; ++n){
    size_t o = (size_t)n*LPH + j;
    float hv = uf(hhi[o]) + uf(hlo[o]);
    float val = fmaxf((hv - mm)*s + bb, 0.f);
    sum += val;
    mx = fmaxf(mx, val);
  }
  int c = hi2 - lo;
  gmean[g*H + j] = (c > 0) ? sum/(float)c : 0.f;
  gmax [g*H + j] = mx;
}

// ---------------- fc1 + bnf + relu ----------------
__global__ __launch_bounds__(256) void fc1_k(
    const float* __restrict__ gmean, const float* __restrict__ gmax,
    const float* __restrict__ W,
    const float* __restrict__ bias,
    const float* __restrict__ fg, const float* __restrict__ fb,
    const float* __restrict__ fm, const float* __restrict__ fv,
    float* __restrict__ out)
{
  int tid = blockIdx.x*256 + threadIdx.x;
  if (tid >= NG*H) return;
  int g = tid / H, j = tid - g*H;
  const float* wr = W + j*2*H;
  float acc = bias[j];
  for (int k = 0; k < H; ++k) acc += gmean[g*H + k] * wr[k];
  for (int k = 0; k < H; ++k) acc += gmax[g*H + k] * wr[H + k];
  float s = fg[j] * rsqrtf(fv[j] + EPSV);
  acc = (acc - fm[j]) * s + fb[j];
  out[tid] = fmaxf(acc, 0.f);
}

__global__ void fc2_k(const float* __restrict__ in, const float* __restrict__ W,
                      const float* __restrict__ bias, float* __restrict__ out)
{
  int tid = blockIdx.x*256 + threadIdx.x;
  if (tid >= NG*2) return;
  int g = tid >> 1, c = tid & 1;
  float acc = bias[c];
  const float* wr = W + c*H;
  const float* xr = in + g*H;
  for (int k = 0; k < H; ++k) acc += xr[k]*wr[k];
  out[tid] = acc;
}

extern "C" void kernel_launch(void* const* d_in, const int* in_sizes, int n_in,
                              void* d_out, int out_size, void* d_ws, size_t ws_size,
                              hipStream_t stream)
{
  const float* x     = (const float*)d_in[0];
  const int*   eidx  = (const int*)d_in[1];
  const int*   batch = (const int*)d_in[2];
  const float* projW = (const float*)d_in[3];
  const float* projb = (const float*)d_in[4];
  const float* bn1g  = (const float*)d_in[5];
  const float* bn1b  = (const float*)d_in[6];
  const float* bn1m  = (const float*)d_in[7];
  const float* bn1v  = (const float*)d_in[8];
  const float* bn2g  = (const float*)d_in[9];
  const float* bn2b  = (const float*)d_in[10];
  const float* bn2m  = (const float*)d_in[11];
  const float* bn2v  = (const float*)d_in[12];
  const float* bnfg  = (const float*)d_in[13];
  const float* bnfb  = (const float*)d_in[14];
  const float* bnfm  = (const float*)d_in[15];
  const float* bnfv  = (const float*)d_in[16];
  const float* ggcW  = (const float*)d_in[17];
  const float* wih   = (const float*)d_in[18];
  const float* whh   = (const float*)d_in[19];
  const float* bih   = (const float*)d_in[20];
  const float* bhh   = (const float*)d_in[21];
  const float* fc1W  = (const float*)d_in[22];
  const float* fc1b  = (const float*)d_in[23];
  const float* fc2W  = (const float*)d_in[24];
  const float* fc2b  = (const float*)d_in[25];

  char* wsp = (char*)d_ws;
  auto alloc = [&](size_t nbytes) {
    char* p = wsp;
    wsp += ((nbytes + 255) / 256) * 256;
    return (void*)p;
  };
  // Node tensors: three pair-regions (hi+lo contiguous) with zeroed 256B guards.
  const size_t PAIRE = (size_t)NN*LPH;            // elements per half
  unsigned short* xaHi = (unsigned short*)alloc(PAIRE*4);
  unsigned short* xaLo = xaHi + PAIRE;
  char* grd0 = (char*)alloc(256);
  unsigned short* hHi  = (unsigned short*)alloc(PAIRE*4);
  unsigned short* hLo  = hHi + PAIRE;
  char* grd1 = (char*)alloc(256);
  unsigned short* mHi  = (unsigned short*)alloc(PAIRE*4);
  unsigned short* mLo  = mHi + PAIRE;
  char* grd2 = (char*)alloc(256);
  // weights (bf16 split, zero-padded to KP)
  unsigned short* pBh   = (unsigned short*)alloc((size_t)H*KP*2);
  unsigned short* pBl   = (unsigned short*)alloc((size_t)H*KP*2);
  unsigned short* wihBh = (unsigned short*)alloc((size_t)3*H*KP*2);
  unsigned short* wihBl = (unsigned short*)alloc((size_t)3*H*KP*2);
  unsigned short* whhBh = (unsigned short*)alloc((size_t)3*H*KP*2);
  unsigned short* whhBl = (unsigned short*)alloc((size_t)3*H*KP*2);
  // per-step: ggc_W[i] non-transposed pair + fused weight Wf_i = wih @ G_i^T pair
  unsigned short* gNTh[3]; unsigned short* gNTl[3];
  unsigned short* wfBh[3]; unsigned short* wfBl[3];
  for (int i = 0; i < 3; ++i) {
    gNTh[i] = (unsigned short*)alloc((size_t)H*KP*2);
    gNTl[i] = (unsigned short*)alloc((size_t)H*KP*2);
    wfBh[i] = (unsigned short*)alloc((size_t)3*H*KP*2);
    wfBl[i] = (unsigned short*)alloc((size_t)3*H*KP*2);
  }
  float* wf32  = (float*)alloc((size_t)3*H*H*4);   // fp32 temp for fused weight
  float* gmean = (float*)alloc((size_t)NG*H*4);
  float* gmax  = (float*)alloc((size_t)NG*H*4);
  float* fc1o  = (float*)alloc((size_t)NG*H*4);
  const int NB = (NN + SCAN_B - 1) / SCAN_B;
  int* deg    = (int*)alloc((size_t)NN*4);
  int* part   = (int*)alloc((size_t)NN*4);
  int* bsum   = (int*)alloc((size_t)NB*4);
  int* rowptr = (int*)alloc((size_t)(NN+1)*4);
  int* cpos   = (int*)alloc((size_t)NN*4);
  int* elist  = (int*)alloc((size_t)NE*4);

  const int* srcp = eidx;
  const int* dstp = eidx + NE;

  // zero the guards (overread landing zones)
  hipMemsetAsync(grd0, 0, 256, stream);
  hipMemsetAsync(grd1, 0, 256, stream);
  hipMemsetAsync(grd2, 0, 256, stream);

  // ---- CSR build (reused all 3 steps) ----
  hipMemsetAsync(deg, 0, (size_t)NN*4, stream);
  hist_k<<<(NE + 255)/256, 256, 0, stream>>>(dstp, deg);
  scan1_k<<<NB, 256, 0, stream>>>(deg, part, bsum, NN);
  scan2_k<<<1, 128, 0, stream>>>(bsum, NB);
  scan3_k<<<(NN + 255)/256, 256, 0, stream>>>(part, bsum, rowptr, cpos, NN);
  fill_k<<<(NE + 255)/256, 256, 0, stream>>>(srcp, dstp, cpos, elist);

  // ---- weight splits (pitch KP, zero-padded) ----
  cvt_split<<<(int)(((long)H*KP + 255)/256), 256, 0, stream>>>(projW, pBh, pBl, H, D, KP);
  cvt_split<<<(int)(((long)3*H*KP + 255)/256), 256, 0, stream>>>(wih, wihBh, wihBl, 3*H, H, KP);
  cvt_split<<<(int)(((long)3*H*KP + 255)/256), 256, 0, stream>>>(whh, whhBh, whhBl, 3*H, H, KP);
  for (int i = 0; i < 3; ++i)
    cvt_split<<<(int)(((long)H*KP + 255)/256), 256, 0, stream>>>(ggcW + (size_t)i*H*H,
                                                                 gNTh[i], gNTl[i], H, H, KP);

  // ---- x -> split pair (pitch LPH, zero-padded pads) ----
  cvt_split<<<(int)(((long)NN*LPH + 255)/256), 256, 0, stream>>>(x, xaHi, xaLo, NN, D, LPH);

  // XCD-grouped grids
  const int NPAN = (NN + 127)/128;            // 782
  const int PL8  = (NPAN + 7)/8;              // 98
  const int NJ_G = (H + 127)/128;             // 2
  const int NJ_U = (H + 31)/32;               // 7
  const int GRID_G = 8 * NJ_G * PL8;
  const int GRID_U = 8 * NJ_U * PL8;
  // prep GEMM grid: M=600 -> 5 panels
  const int NPANW = (3*H + 127)/128;          // 5
  const int GRID_W = 8 * NJ_G * ((NPANW + 7)/8);   // 16

  // ---- fused weights: Wf_i = wih @ G_i^T  ([600,200] fp32 -> split pair [600,KP]) ----
  for (int i = 0; i < 3; ++i) {
    mgemm<0><<<GRID_W, 256, 0, stream>>>(wihBh, wihBl, gNTh[i], gNTl[i],
                                         3*H, H, NJ_G, NPANW, KP, H,
                                         nullptr, nullptr, nullptr, nullptr, nullptr,
                                         nullptr, nullptr, wf32);
    cvt_split<<<(int)(((long)3*H*KP + 255)/256), 256, 0, stream>>>(wf32, wfBh[i], wfBl[i],
                                                                   3*H, H, KP);
  }

  // proj + bn1 + relu : xpair -> hpair (pads zeroed by epilogue)
  mgemm<1><<<GRID_G, 256, 0, stream>>>(xaHi, xaLo, pBh, pBl, NN, H, NJ_G, NPAN, LPH, 0,
                                       projb, bn1g, bn1b, bn1m, bn1v, hHi, hLo, nullptr);

  unsigned short *chHi = hHi, *chLo = hLo, *cmHi = mHi, *cmLo = mLo;
  for (int i = 0; i < 3; ++i) {
    // hg = segment-sum of h rows (pair in, pair out)
    gather_k<<<NN, 256, 0, stream>>>(chHi, chLo, rowptr, elist, xaHi, xaLo);
    // GRU with fused input weights Wf_i (input gates consume hg directly)
    gru6<<<GRID_U, 256, 0, stream>>>(xaHi, xaLo, chHi, chLo,
                                     wfBh[i], wfBl[i], whhBh, whhBl,
                                     bih, bhh, NJ_U, NPAN, cmHi, cmLo);
    unsigned short* t;
    t = chHi; chHi = cmHi; cmHi = t;
    t = chLo; chLo = cmLo; cmLo = t;
  }

  pool_g<<<NG, 256, 0, stream>>>(chHi, chLo, batch, bn2g, bn2b, bn2m, bn2v, gmean, gmax);
  fc1_k<<<(NG*H + 255)/256, 256, 0, stream>>>(gmean, gmax, fc1W, fc1b,
                                              bnfg, bnfb, bnfm, bnfv, fc1o);
  fc2_k<<<(NG*2 + 255)/256, 256, 0, stream>>>(fc1o, fc2W, fc2b, (float*)d_out);
}

// Round 18
// 1906.688 us; speedup vs baseline: 1.2840x; 1.0066x over previous
//
#include <hip/hip_runtime.h>
#include <cmath>

#define NN 100000
#define NE 1600000
#define NG 512
#define H 200
#define D 205
#define EPSV 1e-5f
#define SCAN_B 1024
#define KP 224    // weight k-pitch, bf16, zero-padded
#define LPH 208   // node-buffer k-pitch (elements)
#define GNB 4     // gather: nodes per block

typedef __attribute__((ext_vector_type(8))) short short8v;
typedef __attribute__((ext_vector_type(4))) float f32x4;

#define MFMA16(a,b,c) __builtin_amdgcn_mfma_f32_16x16x32_bf16(a,b,c,0,0,0)

static __device__ __forceinline__ float sigm(float x){ return 1.0f/(1.0f+expf(-x)); }

// split fp32 -> bf16 hi (truncate) + bf16 lo (residual)
static __device__ __forceinline__ void split2(float x, unsigned short& h, unsigned short& l){
  unsigned xb = __float_as_uint(x);
  h = (unsigned short)(xb >> 16);
  float hf = __uint_as_float(xb & 0xffff0000u);
  l = (unsigned short)(__float_as_uint(x - hf) >> 16);
}

static __device__ __forceinline__ float uf(unsigned short u){
  return __uint_as_float(((unsigned)u) << 16);
}

static __device__ __forceinline__ void gload16(const void* src, void* dst){
  __builtin_amdgcn_global_load_lds(
      (const __attribute__((address_space(1))) unsigned int*)src,
      (__attribute__((address_space(3))) unsigned int*)dst, 16, 0, 0);
}

// ---------------- cvt fp32 [rows,C] -> hi/lo bf16 [rows,P], zero-padded ----------------
__global__ __launch_bounds__(256) void cvt_split(const float* __restrict__ in,
    unsigned short* __restrict__ hi, unsigned short* __restrict__ lo, int rows, int C, int P){
  long i = (long)blockIdx.x*256 + threadIdx.x;
  long tot = (long)rows*P;
  if (i >= tot) return;
  int r = (int)(i/P), c = (int)(i - (long)r*P);
  float v = (c < C) ? in[(size_t)r*C + c] : 0.f;
  unsigned short hh, ll; split2(v,hh,ll);
  hi[i] = hh; lo[i] = ll;
}

// ---------------- split-bf16 MFMA GEMM, single-barrier double-buffered pipeline -------
template<int EPIL>
__global__ __launch_bounds__(256) void mgemm(
    const unsigned short* __restrict__ Ahi, const unsigned short* __restrict__ Alo,
    const unsigned short* __restrict__ Bhi, const unsigned short* __restrict__ Blo,
    int M, int N, int nj, int npan, int LPA, int LPC,
    const float* __restrict__ bias,
    const float* __restrict__ bg, const float* __restrict__ bb,
    const float* __restrict__ bm, const float* __restrict__ bv,
    unsigned short* __restrict__ Chi, unsigned short* __restrict__ Clo,
    float* __restrict__ Cf)
{
  __shared__ __align__(16) char S[2][16384];   // per buf: Bhi 0..8K, Blo 8K..16K
  const int bid = blockIdx.x;
  const int xcd = bid & 7, sl = bid >> 3;
  const int pl = sl / nj, jj = sl - pl*nj;
  const int p = pl*8 + xcd;
  if (p >= npan) return;
  const int n0 = jj*128, r0 = p*128;
  const int tid = threadIdx.x, lane = tid & 63, wave = tid >> 6;
  const int wr = (wave>>1)*64, wc = (wave&1)*64;
  const int fr = lane & 15, fq = lane >> 4;
  f32x4 acc[4][4] = {};

  const unsigned short* sp[4]; int sdst[4];
  #pragma unroll
  for (int i = 0; i < 4; ++i) {
    int g = wave + 4*i;                 // 0..15
    int region = g >> 3, c = g & 7, rowgrp = c >> 2, q = c & 3;
    int row = rowgrp*64 + lane;
    int rg = n0 + row; if (rg > N-1) rg = N-1;
    sp[i] = (region ? Blo : Bhi) + (size_t)rg*KP + q*8;
    sdst[i] = region*8192 + q*2048 + rowgrp*1024;
  }
  int arow[4];
  #pragma unroll
  for (int t = 0; t < 4; ++t) {
    int rg = r0 + wr + t*16 + fr; if (rg > M-1) rg = M-1;
    arow[t] = rg*LPA + fq*8;
  }

  short8v AH[4], AL[4], NH[4], NL[4];
  #pragma unroll
  for (int i = 0; i < 4; ++i) gload16(sp[i], S[0] + sdst[i]);
  #pragma unroll
  for (int t = 0; t < 4; ++t) {
    AH[t] = *(const short8v*)(Ahi + arow[t]);
    AL[t] = *(const short8v*)(Alo + arow[t]);
  }
  __syncthreads();

  #pragma unroll
  for (int kk = 0; kk < 7; ++kk) {
    const int kb = kk & 1;
    if (kk < 6) {
      const int kn = (kk+1)*32;
      #pragma unroll
      for (int i = 0; i < 4; ++i) gload16(sp[i] + kn, S[kb^1] + sdst[i]);
      #pragma unroll
      for (int t = 0; t < 4; ++t) {
        NH[t] = *(const short8v*)(Ahi + arow[t] + kn);
        NL[t] = *(const short8v*)(Alo + arow[t] + kn);
      }
    }
    short8v bh[4], bl[4];
    #pragma unroll
    for (int t = 0; t < 4; ++t) {
      int rb = (wc + t*16 + fr)*16;
      bh[t] = *(const short8v*)(S[kb] +    0 + fq*2048 + rb);
      bl[t] = *(const short8v*)(S[kb] + 8192 + fq*2048 + rb);
    }
    #pragma unroll
    for (int i = 0; i < 4; ++i)
      #pragma unroll
      for (int j = 0; j < 4; ++j) {
        acc[i][j] = MFMA16(AH[i], bh[j], acc[i][j]);
        acc[i][j] = MFMA16(AH[i], bl[j], acc[i][j]);
        acc[i][j] = MFMA16(AL[i], bh[j], acc[i][j]);
      }
    __syncthreads();
    if (kk < 6) {
      #pragma unroll
      for (int t = 0; t < 4; ++t) { AH[t] = NH[t]; AL[t] = NL[t]; }
    }
  }

  #pragma unroll
  for (int i = 0; i < 4; ++i)
    #pragma unroll
    for (int j = 0; j < 4; ++j)
      #pragma unroll
      for (int q = 0; q < 4; ++q) {
        int row = r0 + wr + i*16 + fq*4 + q;
        int col = n0 + wc + j*16 + fr;
        if (row < M && col < N) {
          float c = acc[i][j][q];
          if (EPIL) {
            c += bias[col];
            c = (c - bm[col]) * (bg[col] * rsqrtf(bv[col] + EPSV)) + bb[col];
            c = fmaxf(c, 0.f);
            unsigned short hh, ll; split2(c, hh, ll);
            size_t o = (size_t)row*LPH + col;
            Chi[o] = hh; Clo[o] = ll;
          } else {
            Cf[(size_t)row*LPC + col] = c;
          }
        } else if (EPIL && row < M && col >= N && col < LPH) {
          size_t o = (size_t)row*LPH + col;
          Chi[o] = 0; Clo[o] = 0;
        }
      }
}

// ---------------- fused GRU: 4-acc, single-barrier double-buffered pipeline -----------
__global__ __launch_bounds__(256, 2) void gru6(
    const unsigned short* __restrict__ Ghi, const unsigned short* __restrict__ Glo,
    const unsigned short* __restrict__ Hhi, const unsigned short* __restrict__ Hlo,
    const unsigned short* __restrict__ Wihh, const unsigned short* __restrict__ Wihl,
    const unsigned short* __restrict__ Whhh, const unsigned short* __restrict__ Whhl,
    const float* __restrict__ bih, const float* __restrict__ bhh,
    int nj, int npan,
    unsigned short* __restrict__ Ohi, unsigned short* __restrict__ Olo)
{
  __shared__ __align__(16) char S[2][24576];   // per buf: Ws0 0..12K, Ws1 12K..24K
  const int bid = blockIdx.x;
  const int xcd = bid & 7, sl = bid >> 3;
  const int pl = sl / nj, jt = sl - pl*nj;
  const int p = pl*8 + xcd;
  if (p >= npan) return;
  const int j0 = jt*32, r0 = p*128;
  const int tid = threadIdx.x, lane = tid & 63, wave = tid >> 6;
  const int fr = lane & 15, fq = lane >> 4;
  f32x4 acc[4][2][2] = {};   // [0]=r(i+h), [1]=z(i+h), [2]=n-in, [3]=n-hid

  const unsigned short* sp[6]; int sdst[6];
  #pragma unroll
  for (int i = 0; i < 6; ++i) {
    int g = wave + 4*i;                 // 0..23
    int comp = g / 12, c = g - comp*12, rowgrp = c >> 2, q = c & 3;
    int R = rowgrp*64 + lane, gate = R>>5, jjj = R&31;
    int g3 = (gate >= 3) ? gate-3 : gate;
    int jcol = j0 + jjj; if (jcol > H-1) jcol = H-1;
    const unsigned short* base = (gate < 3) ? (comp ? Wihl : Wihh) : (comp ? Whhl : Whhh);
    sp[i] = base + (size_t)(g3*H + jcol)*KP + q*8;
    sdst[i] = comp*12288 + q*3072 + rowgrp*1024;
  }
  int arow[2];
  #pragma unroll
  for (int t = 0; t < 2; ++t) {
    int rg = r0 + wave*32 + t*16 + fr; if (rg > NN-1) rg = NN-1;
    arow[t] = rg*LPH + fq*8;
  }

  short8v Ac[4][2], An[4][2];   // [comp: g-hi, g-lo, h-hi, h-lo][t]
  #pragma unroll
  for (int i = 0; i < 6; ++i) gload16(sp[i], S[0] + sdst[i]);
  #pragma unroll
  for (int t = 0; t < 2; ++t) {
    Ac[0][t] = *(const short8v*)(Ghi + arow[t]);
    Ac[1][t] = *(const short8v*)(Glo + arow[t]);
    Ac[2][t] = *(const short8v*)(Hhi + arow[t]);
    Ac[3][t] = *(const short8v*)(Hlo + arow[t]);
  }
  __syncthreads();

  #pragma unroll
  for (int kk = 0; kk < 7; ++kk) {
    const int kb = kk & 1;
    if (kk < 6) {
      const int kn = (kk+1)*32;
      #pragma unroll
      for (int i = 0; i < 6; ++i) gload16(sp[i] + kn, S[kb^1] + sdst[i]);
      #pragma unroll
      for (int t = 0; t < 2; ++t) {
        An[0][t] = *(const short8v*)(Ghi + arow[t] + kn);
        An[1][t] = *(const short8v*)(Glo + arow[t] + kn);
        An[2][t] = *(const short8v*)(Hhi + arow[t] + kn);
        An[3][t] = *(const short8v*)(Hlo + arow[t] + kn);
      }
    }
    const char* w0 = S[kb] +     0 + fq*3072;
    const char* w1 = S[kb] + 12288 + fq*3072;
    #pragma unroll
    for (int g = 0; g < 6; ++g) {
      short8v b0h = *(const short8v*)(w0 + (g*32      + fr)*16);
      short8v b1h = *(const short8v*)(w0 + (g*32 + 16 + fr)*16);
      short8v b0l = *(const short8v*)(w1 + (g*32      + fr)*16);
      short8v b1l = *(const short8v*)(w1 + (g*32 + 16 + fr)*16);
      const int ai = (g < 3) ? 0 : 2;               // input path vs hidden path
      const int ac = (g == 5) ? 3 : (g % 3);        // r,z shared; n-in=2, n-hid=3
      #pragma unroll
      for (int t = 0; t < 2; ++t) {
        acc[ac][t][0] = MFMA16(Ac[ai][t],   b0h, acc[ac][t][0]);
        acc[ac][t][0] = MFMA16(Ac[ai][t],   b0l, acc[ac][t][0]);
        acc[ac][t][0] = MFMA16(Ac[ai+1][t], b0h, acc[ac][t][0]);
        acc[ac][t][1] = MFMA16(Ac[ai][t],   b1h, acc[ac][t][1]);
        acc[ac][t][1] = MFMA16(Ac[ai][t],   b1l, acc[ac][t][1]);
        acc[ac][t][1] = MFMA16(Ac[ai+1][t], b1h, acc[ac][t][1]);
      }
    }
    __syncthreads();
    if (kk < 6) {
      #pragma unroll
      for (int c2 = 0; c2 < 4; ++c2)
        #pragma unroll
        for (int t = 0; t < 2; ++t) Ac[c2][t] = An[c2][t];
    }
  }

  #pragma unroll
  for (int ct = 0; ct < 2; ++ct) {
    int j = j0 + ct*16 + fr;
    if (j >= LPH) continue;
    if (j >= H) {
      #pragma unroll
      for (int t = 0; t < 2; ++t)
        #pragma unroll
        for (int q = 0; q < 4; ++q) {
          int row = r0 + wave*32 + t*16 + fq*4 + q;
          if (row >= NN) continue;
          size_t o = (size_t)row*LPH + j;
          Ohi[o] = 0; Olo[o] = 0;
        }
      continue;
    }
    float br  = bih[j]     + bhh[j];
    float bz  = bih[H+j]   + bhh[H+j];
    float bin = bih[2*H+j], bhn = bhh[2*H+j];
    #pragma unroll
    for (int t = 0; t < 2; ++t)
      #pragma unroll
      for (int q = 0; q < 4; ++q) {
        int row = r0 + wave*32 + t*16 + fq*4 + q;
        if (row >= NN) continue;
        float rv = sigm(acc[0][t][ct][q] + br);
        float zv = sigm(acc[1][t][ct][q] + bz);
        float nv = tanhf(acc[2][t][ct][q] + bin + rv*(acc[3][t][ct][q] + bhn));
        size_t o = (size_t)row*LPH + j;
        float ho = uf(Hhi[o]) + uf(Hlo[o]);
        unsigned short hh2, ll2; split2((1.f - zv)*nv + zv*ho, hh2, ll2);
        Ohi[o] = hh2; Olo[o] = ll2;
      }
  }
}

// ---------------- CSR build ----------------
__global__ __launch_bounds__(256) void hist_k(const int* __restrict__ dst, int* __restrict__ deg){
  int e = blockIdx.x*256 + threadIdx.x;
  if (e < NE) atomicAdd(&deg[dst[e]], 1);
}

__global__ __launch_bounds__(256) void scan1_k(const int* __restrict__ deg, int* __restrict__ part,
                                               int* __restrict__ bsum, int n){
  __shared__ int lds[256];
  int t = threadIdx.x;
  int base = blockIdx.x * SCAN_B + t*4;
  int v[4]; int s = 0;
  #pragma unroll
  for (int q = 0; q < 4; ++q){ int idx = base+q; v[q] = (idx < n) ? deg[idx] : 0; s += v[q]; }
  lds[t] = s;
  __syncthreads();
  for (int off = 1; off < 256; off <<= 1){
    int val = 0;
    if (t >= off) val = lds[t-off];
    __syncthreads();
    if (t >= off) lds[t] += val;
    __syncthreads();
  }
  if (t == 255) bsum[blockIdx.x] = lds[255];
  int run = (t == 0) ? 0 : lds[t-1];
  #pragma unroll
  for (int q = 0; q < 4; ++q){ int idx = base+q; if (idx < n) part[idx] = run; run += v[q]; }
}

__global__ void scan2_k(int* __restrict__ bsum, int nb){
  __shared__ int lds[128];
  int t = threadIdx.x;
  int v = (t < nb) ? bsum[t] : 0;
  lds[t] = v;
  __syncthreads();
  for (int off = 1; off < 128; off <<= 1){
    int val = 0;
    if (t >= off) val = lds[t-off];
    __syncthreads();
    if (t >= off) lds[t] += val;
    __syncthreads();
  }
  if (t < nb) bsum[t] = (t == 0) ? 0 : lds[t-1];
}

__global__ __launch_bounds__(256) void scan3_k(const int* __restrict__ part, const int* __restrict__ bsum,
                                               int* __restrict__ rowptr, int* __restrict__ cpos, int n){
  int i = blockIdx.x*256 + threadIdx.x;
  if (i < n){
    int v = part[i] + bsum[i >> 10];
    rowptr[i] = v;
    cpos[i] = v;
  }
  if (i == 0) rowptr[n] = NE;
}

__global__ __launch_bounds__(256) void fill_k(const int* __restrict__ src, const int* __restrict__ dst,
                                              int* __restrict__ cpos, int* __restrict__ elist){
  int e = blockIdx.x*256 + threadIdx.x;
  if (e < NE){
    int p = atomicAdd(&cpos[dst[e]], 1);
    elist[p] = src[e];
  }
}

// ---------------- gather: GNB nodes/block, no LDS/barriers, uniform elist broadcast ----
__global__ __launch_bounds__(256) void gather_k(const unsigned short* __restrict__ mhi,
                                                const unsigned short* __restrict__ mlo,
                                                const int* __restrict__ rowptr,
                                                const int* __restrict__ elist,
                                                unsigned short* __restrict__ ahi,
                                                unsigned short* __restrict__ alo){
  int j = threadIdx.x;
  if (j >= H) return;
  int nb = blockIdx.x * GNB;
  #pragma unroll
  for (int u = 0; u < GNB; ++u){
    int n = nb + u;
    if (n >= NN) break;
    int beg = rowptr[n], end = rowptr[n+1];
    float a0=0.f, a1=0.f, a2=0.f, a3=0.f;
    int k = beg;
    for (; k + 4 <= end; k += 4){
      size_t s0 = (size_t)elist[k  ]*LPH + j;
      size_t s1 = (size_t)elist[k+1]*LPH + j;
      size_t s2 = (size_t)elist[k+2]*LPH + j;
      size_t s3 = (size_t)elist[k+3]*LPH + j;
      a0 += uf(mhi[s0]) + uf(mlo[s0]);
      a1 += uf(mhi[s1]) + uf(mlo[s1]);
      a2 += uf(mhi[s2]) + uf(mlo[s2]);
      a3 += uf(mhi[s3]) + uf(mlo[s3]);
    }
    for (; k < end; ++k){
      size_t s = (size_t)elist[k]*LPH + j;
      a0 += uf(mhi[s]) + uf(mlo[s]);
    }
    unsigned short hh, ll; split2((a0 + a1) + (a2 + a3), hh, ll);
    size_t o = (size_t)n*LPH + j;
    ahi[o] = hh; alo[o] = ll;
  }
}

// ---------------- pooling: one block per graph (batch sorted) ----------------
__global__ __launch_bounds__(256) void pool_g(
    const unsigned short* __restrict__ hhi, const unsigned short* __restrict__ hlo,
    const int* __restrict__ batch,
    const float* __restrict__ g2, const float* __restrict__ b2,
    const float* __restrict__ m2, const float* __restrict__ v2,
    float* __restrict__ gmean, float* __restrict__ gmax)
{
  int g = blockIdx.x;
  int lo = 0, hi = NN;
  while (lo < hi){ int mid = (lo+hi)>>1; if (batch[mid] < g) lo = mid+1; else hi = mid; }
  int lo2 = lo, hi2 = NN;
  while (lo2 < hi2){ int mid = (lo2+hi2)>>1; if (batch[mid] < g+1) lo2 = mid+1; else hi2 = mid; }
  int j = threadIdx.x;
  if (j >= H) return;
  float s = g2[j] * rsqrtf(v2[j] + EPSV);
  float mm = m2[j], bb = b2[j];
  float sum = 0.f, mx = 0.f;
  for (int n = lo; n < hi2; ++n){
    size_t o = (size_t)n*LPH + j;
    float hv = uf(hhi[o]) + uf(hlo[o]);
    float val = fmaxf((hv - mm)*s + bb, 0.f);
    sum += val;
    mx = fmaxf(mx, val);
  }
  int c = hi2 - lo;
  gmean[g*H + j] = (c > 0) ? sum/(float)c : 0.f;
  gmax [g*H + j] = mx;
}

// ---------------- fc1 + bnf + relu ----------------
__global__ __launch_bounds__(256) void fc1_k(
    const float* __restrict__ gmean, const float* __restrict__ gmax,
    const float* __restrict__ W,
    const float* __restrict__ bias,
    const float* __restrict__ fg, const float* __restrict__ fb,
    const float* __restrict__ fm, const float* __restrict__ fv,
    float* __restrict__ out)
{
  int tid = blockIdx.x*256 + threadIdx.x;
  if (tid >= NG*H) return;
  int g = tid / H, j = tid - g*H;
  const float* wr = W + j*2*H;
  float acc = bias[j];
  for (int k = 0; k < H; ++k) acc += gmean[g*H + k] * wr[k];
  for (int k = 0; k < H; ++k) acc += gmax[g*H + k] * wr[H + k];
  float s = fg[j] * rsqrtf(fv[j] + EPSV);
  acc = (acc - fm[j]) * s + fb[j];
  out[tid] = fmaxf(acc, 0.f);
}

__global__ void fc2_k(const float* __restrict__ in, const float* __restrict__ W,
                      const float* __restrict__ bias, float* __restrict__ out)
{
  int tid = blockIdx.x*256 + threadIdx.x;
  if (tid >= NG*2) return;
  int g = tid >> 1, c = tid & 1;
  float acc = bias[c];
  const float* wr = W + c*H;
  const float* xr = in + g*H;
  for (int k = 0; k < H; ++k) acc += xr[k]*wr[k];
  out[tid] = acc;
}

extern "C" void kernel_launch(void* const* d_in, const int* in_sizes, int n_in,
                              void* d_out, int out_size, void* d_ws, size_t ws_size,
                              hipStream_t stream)
{
  const float* x     = (const float*)d_in[0];
  const int*   eidx  = (const int*)d_in[1];
  const int*   batch = (const int*)d_in[2];
  const float* projW = (const float*)d_in[3];
  const float* projb = (const float*)d_in[4];
  const float* bn1g  = (const float*)d_in[5];
  const float* bn1b  = (const float*)d_in[6];
  const float* bn1m  = (const float*)d_in[7];
  const float* bn1v  = (const float*)d_in[8];
  const float* bn2g  = (const float*)d_in[9];
  const float* bn2b  = (const float*)d_in[10];
  const float* bn2m  = (const float*)d_in[11];
  const float* bn2v  = (const float*)d_in[12];
  const float* bnfg  = (const float*)d_in[13];
  const float* bnfb  = (const float*)d_in[14];
  const float* bnfm  = (const float*)d_in[15];
  const float* bnfv  = (const float*)d_in[16];
  const float* ggcW  = (const float*)d_in[17];
  const float* wih   = (const float*)d_in[18];
  const float* whh   = (const float*)d_in[19];
  const float* bih   = (const float*)d_in[20];
  const float* bhh   = (const float*)d_in[21];
  const float* fc1W  = (const float*)d_in[22];
  const float* fc1b  = (const float*)d_in[23];
  const float* fc2W  = (const float*)d_in[24];
  const float* fc2b  = (const float*)d_in[25];

  char* wsp = (char*)d_ws;
  auto alloc = [&](size_t nbytes) {
    char* p = wsp;
    wsp += ((nbytes + 255) / 256) * 256;
    return (void*)p;
  };
  // Node tensors: three pair-regions (hi+lo contiguous) with zeroed 256B guards.
  const size_t PAIRE = (size_t)NN*LPH;            // elements per half
  unsigned short* xaHi = (unsigned short*)alloc(PAIRE*4);
  unsigned short* xaLo = xaHi + PAIRE;
  char* grd0 = (char*)alloc(256);
  unsigned short* hHi  = (unsigned short*)alloc(PAIRE*4);
  unsigned short* hLo  = hHi + PAIRE;
  char* grd1 = (char*)alloc(256);
  unsigned short* mHi  = (unsigned short*)alloc(PAIRE*4);
  unsigned short* mLo  = mHi + PAIRE;
  char* grd2 = (char*)alloc(256);
  // weights (bf16 split, zero-padded to KP)
  unsigned short* pBh   = (unsigned short*)alloc((size_t)H*KP*2);
  unsigned short* pBl   = (unsigned short*)alloc((size_t)H*KP*2);
  unsigned short* wihBh = (unsigned short*)alloc((size_t)3*H*KP*2);
  unsigned short* wihBl = (unsigned short*)alloc((size_t)3*H*KP*2);
  unsigned short* whhBh = (unsigned short*)alloc((size_t)3*H*KP*2);
  unsigned short* whhBl = (unsigned short*)alloc((size_t)3*H*KP*2);
  // per-step: ggc_W[i] non-transposed pair + fused weight Wf_i = wih @ G_i^T pair
  unsigned short* gNTh[3]; unsigned short* gNTl[3];
  unsigned short* wfBh[3]; unsigned short* wfBl[3];
  for (int i = 0; i < 3; ++i) {
    gNTh[i] = (unsigned short*)alloc((size_t)H*KP*2);
    gNTl[i] = (unsigned short*)alloc((size_t)H*KP*2);
    wfBh[i] = (unsigned short*)alloc((size_t)3*H*KP*2);
    wfBl[i] = (unsigned short*)alloc((size_t)3*H*KP*2);
  }
  float* wf32  = (float*)alloc((size_t)3*H*H*4);   // fp32 temp for fused weight
  float* gmean = (float*)alloc((size_t)NG*H*4);
  float* gmax  = (float*)alloc((size_t)NG*H*4);
  float* fc1o  = (float*)alloc((size_t)NG*H*4);
  const int NB = (NN + SCAN_B - 1) / SCAN_B;
  int* deg    = (int*)alloc((size_t)NN*4);
  int* part   = (int*)alloc((size_t)NN*4);
  int* bsum   = (int*)alloc((size_t)NB*4);
  int* rowptr = (int*)alloc((size_t)(NN+1)*4);
  int* cpos   = (int*)alloc((size_t)NN*4);
  int* elist  = (int*)alloc((size_t)NE*4);

  const int* srcp = eidx;
  const int* dstp = eidx + NE;

  // zero the guards (overread landing zones)
  hipMemsetAsync(grd0, 0, 256, stream);
  hipMemsetAsync(grd1, 0, 256, stream);
  hipMemsetAsync(grd2, 0, 256, stream);

  // ---- CSR build (reused all 3 steps) ----
  hipMemsetAsync(deg, 0, (size_t)NN*4, stream);
  hist_k<<<(NE + 255)/256, 256, 0, stream>>>(dstp, deg);
  scan1_k<<<NB, 256, 0, stream>>>(deg, part, bsum, NN);
  scan2_k<<<1, 128, 0, stream>>>(bsum, NB);
  scan3_k<<<(NN + 255)/256, 256, 0, stream>>>(part, bsum, rowptr, cpos, NN);
  fill_k<<<(NE + 255)/256, 256, 0, stream>>>(srcp, dstp, cpos, elist);

  // ---- weight splits (pitch KP, zero-padded) ----
  cvt_split<<<(int)(((long)H*KP + 255)/256), 256, 0, stream>>>(projW, pBh, pBl, H, D, KP);
  cvt_split<<<(int)(((long)3*H*KP + 255)/256), 256, 0, stream>>>(wih, wihBh, wihBl, 3*H, H, KP);
  cvt_split<<<(int)(((long)3*H*KP + 255)/256), 256, 0, stream>>>(whh, whhBh, whhBl, 3*H, H, KP);
  for (int i = 0; i < 3; ++i)
    cvt_split<<<(int)(((long)H*KP + 255)/256), 256, 0, stream>>>(ggcW + (size_t)i*H*H,
                                                                 gNTh[i], gNTl[i], H, H, KP);

  // ---- x -> split pair (pitch LPH, zero-padded pads) ----
  cvt_split<<<(int)(((long)NN*LPH + 255)/256), 256, 0, stream>>>(x, xaHi, xaLo, NN, D, LPH);

  // XCD-grouped grids
  const int NPAN = (NN + 127)/128;            // 782
  const int PL8  = (NPAN + 7)/8;              // 98
  const int NJ_G = (H + 127)/128;             // 2
  const int NJ_U = (H + 31)/32;               // 7
  const int GRID_G = 8 * NJ_G * PL8;
  const int GRID_U = 8 * NJ_U * PL8;
  const int NPANW = (3*H + 127)/128;          // 5
  const int GRID_W = 8 * NJ_G * ((NPANW + 7)/8);

  // ---- fused weights: Wf_i = wih @ G_i^T ----
  for (int i = 0; i < 3; ++i) {
    mgemm<0><<<GRID_W, 256, 0, stream>>>(wihBh, wihBl, gNTh[i], gNTl[i],
                                         3*H, H, NJ_G, NPANW, KP, H,
                                         nullptr, nullptr, nullptr, nullptr, nullptr,
                                         nullptr, nullptr, wf32);
    cvt_split<<<(int)(((long)3*H*KP + 255)/256), 256, 0, stream>>>(wf32, wfBh[i], wfBl[i],
                                                                   3*H, H, KP);
  }

  // proj + bn1 + relu : xpair -> hpair (pads zeroed by epilogue)
  mgemm<1><<<GRID_G, 256, 0, stream>>>(xaHi, xaLo, pBh, pBl, NN, H, NJ_G, NPAN, LPH, 0,
                                       projb, bn1g, bn1b, bn1m, bn1v, hHi, hLo, nullptr);

  unsigned short *chHi = hHi, *chLo = hLo, *cmHi = mHi, *cmLo = mLo;
  for (int i = 0; i < 3; ++i) {
    gather_k<<<(NN + GNB - 1)/GNB, 256, 0, stream>>>(chHi, chLo, rowptr, elist, xaHi, xaLo);
    gru6<<<GRID_U, 256, 0, stream>>>(xaHi, xaLo, chHi, chLo,
                                     wfBh[i], wfBl[i], whhBh, whhBl,
                                     bih, bhh, NJ_U, NPAN, cmHi, cmLo);
    unsigned short* t;
    t = chHi; chHi = cmHi; cmHi = t;
    t = chLo; chLo = cmLo; cmLo = t;
  }

  pool_g<<<NG, 256, 0, stream>>>(chHi, chLo, batch, bn2g, bn2b, bn2m, bn2v, gmean, gmax);
  fc1_k<<<(NG*H + 255)/256, 256, 0, stream>>>(gmean, gmax, fc1W, fc1b,
                                              bnfg, bnfb, bnfm, bnfv, fc1o);
  fc2_k<<<(NG*2 + 255)/256, 256, 0, stream>>>(fc1o, fc2W, fc2b, (float*)d_out);
}

// Round 19
// 1853.920 us; speedup vs baseline: 1.3205x; 1.0285x over previous
//
#include <hip/hip_runtime.h>
#include <cmath>

#define NN 100000
#define NE 1600000
#define NG 512
#define H 200
#define D 205
#define EPSV 1e-5f
#define SCAN_B 1024
#define KP 224    // weight k-pitch, bf16, zero-padded
#define LPH 208   // node-buffer k-pitch (elements)
#define GNB 4     // gather: nodes per block (processed 2 at a time)

typedef __attribute__((ext_vector_type(8))) short short8v;
typedef __attribute__((ext_vector_type(4))) float f32x4;

#define MFMA16(a,b,c) __builtin_amdgcn_mfma_f32_16x16x32_bf16(a,b,c,0,0,0)

static __device__ __forceinline__ float sigm(float x){ return 1.0f/(1.0f+expf(-x)); }

// split fp32 -> bf16 hi (truncate) + bf16 lo (residual)
static __device__ __forceinline__ void split2(float x, unsigned short& h, unsigned short& l){
  unsigned xb = __float_as_uint(x);
  h = (unsigned short)(xb >> 16);
  float hf = __uint_as_float(xb & 0xffff0000u);
  l = (unsigned short)(__float_as_uint(x - hf) >> 16);
}

static __device__ __forceinline__ float uf(unsigned short u){
  return __uint_as_float(((unsigned)u) << 16);
}

static __device__ __forceinline__ void gload16(const void* src, void* dst){
  __builtin_amdgcn_global_load_lds(
      (const __attribute__((address_space(1))) unsigned int*)src,
      (__attribute__((address_space(3))) unsigned int*)dst, 16, 0, 0);
}

// ---------------- cvt fp32 [rows,C] -> hi/lo bf16 [rows,P], zero-padded ----------------
__global__ __launch_bounds__(256) void cvt_split(const float* __restrict__ in,
    unsigned short* __restrict__ hi, unsigned short* __restrict__ lo, int rows, int C, int P){
  long i = (long)blockIdx.x*256 + threadIdx.x;
  long tot = (long)rows*P;
  if (i >= tot) return;
  int r = (int)(i/P), c = (int)(i - (long)r*P);
  float v = (c < C) ? in[(size_t)r*C + c] : 0.f;
  unsigned short hh, ll; split2(v,hh,ll);
  hi[i] = hh; lo[i] = ll;
}

// ---------------- split-bf16 MFMA GEMM, single-barrier double-buffered pipeline -------
template<int EPIL>
__global__ __launch_bounds__(256) void mgemm(
    const unsigned short* __restrict__ Ahi, const unsigned short* __restrict__ Alo,
    const unsigned short* __restrict__ Bhi, const unsigned short* __restrict__ Blo,
    int M, int N, int nj, int npan, int LPA, int LPC,
    const float* __restrict__ bias,
    const float* __restrict__ bg, const float* __restrict__ bb,
    const float* __restrict__ bm, const float* __restrict__ bv,
    unsigned short* __restrict__ Chi, unsigned short* __restrict__ Clo,
    float* __restrict__ Cf)
{
  __shared__ __align__(16) char S[2][16384];   // per buf: Bhi 0..8K, Blo 8K..16K
  const int bid = blockIdx.x;
  const int xcd = bid & 7, sl = bid >> 3;
  const int pl = sl / nj, jj = sl - pl*nj;
  const int p = pl*8 + xcd;
  if (p >= npan) return;
  const int n0 = jj*128, r0 = p*128;
  const int tid = threadIdx.x, lane = tid & 63, wave = tid >> 6;
  const int wr = (wave>>1)*64, wc = (wave&1)*64;
  const int fr = lane & 15, fq = lane >> 4;
  f32x4 acc[4][4] = {};

  const unsigned short* sp[4]; int sdst[4];
  #pragma unroll
  for (int i = 0; i < 4; ++i) {
    int g = wave + 4*i;                 // 0..15
    int region = g >> 3, c = g & 7, rowgrp = c >> 2, q = c & 3;
    int row = rowgrp*64 + lane;
    int rg = n0 + row; if (rg > N-1) rg = N-1;
    sp[i] = (region ? Blo : Bhi) + (size_t)rg*KP + q*8;
    sdst[i] = region*8192 + q*2048 + rowgrp*1024;
  }
  int arow[4];
  #pragma unroll
  for (int t = 0; t < 4; ++t) {
    int rg = r0 + wr + t*16 + fr; if (rg > M-1) rg = M-1;
    arow[t] = rg*LPA + fq*8;
  }

  short8v AH[4], AL[4], NH[4], NL[4];
  #pragma unroll
  for (int i = 0; i < 4; ++i) gload16(sp[i], S[0] + sdst[i]);
  #pragma unroll
  for (int t = 0; t < 4; ++t) {
    AH[t] = *(const short8v*)(Ahi + arow[t]);
    AL[t] = *(const short8v*)(Alo + arow[t]);
  }
  __syncthreads();

  #pragma unroll
  for (int kk = 0; kk < 7; ++kk) {
    const int kb = kk & 1;
    if (kk < 6) {
      const int kn = (kk+1)*32;
      #pragma unroll
      for (int i = 0; i < 4; ++i) gload16(sp[i] + kn, S[kb^1] + sdst[i]);
      #pragma unroll
      for (int t = 0; t < 4; ++t) {
        NH[t] = *(const short8v*)(Ahi + arow[t] + kn);
        NL[t] = *(const short8v*)(Alo + arow[t] + kn);
      }
    }
    short8v bh[4], bl[4];
    #pragma unroll
    for (int t = 0; t < 4; ++t) {
      int rb = (wc + t*16 + fr)*16;
      bh[t] = *(const short8v*)(S[kb] +    0 + fq*2048 + rb);
      bl[t] = *(const short8v*)(S[kb] + 8192 + fq*2048 + rb);
    }
    #pragma unroll
    for (int i = 0; i < 4; ++i)
      #pragma unroll
      for (int j = 0; j < 4; ++j) {
        acc[i][j] = MFMA16(AH[i], bh[j], acc[i][j]);
        acc[i][j] = MFMA16(AH[i], bl[j], acc[i][j]);
        acc[i][j] = MFMA16(AL[i], bh[j], acc[i][j]);
      }
    __syncthreads();
    if (kk < 6) {
      #pragma unroll
      for (int t = 0; t < 4; ++t) { AH[t] = NH[t]; AL[t] = NL[t]; }
    }
  }

  #pragma unroll
  for (int i = 0; i < 4; ++i)
    #pragma unroll
    for (int j = 0; j < 4; ++j)
      #pragma unroll
      for (int q = 0; q < 4; ++q) {
        int row = r0 + wr + i*16 + fq*4 + q;
        int col = n0 + wc + j*16 + fr;
        if (row < M && col < N) {
          float c = acc[i][j][q];
          if (EPIL) {
            c += bias[col];
            c = (c - bm[col]) * (bg[col] * rsqrtf(bv[col] + EPSV)) + bb[col];
            c = fmaxf(c, 0.f);
            unsigned short hh, ll; split2(c, hh, ll);
            size_t o = (size_t)row*LPH + col;
            Chi[o] = hh; Clo[o] = ll;
          } else {
            Cf[(size_t)row*LPC + col] = c;
          }
        } else if (EPIL && row < M && col >= N && col < LPH) {
          size_t o = (size_t)row*LPH + col;
          Chi[o] = 0; Clo[o] = 0;
        }
      }
}

// ---------------- fused GRU: 4-acc, single-barrier double-buffered pipeline -----------
__global__ __launch_bounds__(256, 2) void gru6(
    const unsigned short* __restrict__ Ghi, const unsigned short* __restrict__ Glo,
    const unsigned short* __restrict__ Hhi, const unsigned short* __restrict__ Hlo,
    const unsigned short* __restrict__ Wihh, const unsigned short* __restrict__ Wihl,
    const unsigned short* __restrict__ Whhh, const unsigned short* __restrict__ Whhl,
    const float* __restrict__ bih, const float* __restrict__ bhh,
    int nj, int npan,
    unsigned short* __restrict__ Ohi, unsigned short* __restrict__ Olo)
{
  __shared__ __align__(16) char S[2][24576];   // per buf: Ws0 0..12K, Ws1 12K..24K
  const int bid = blockIdx.x;
  const int xcd = bid & 7, sl = bid >> 3;
  const int pl = sl / nj, jt = sl - pl*nj;
  const int p = pl*8 + xcd;
  if (p >= npan) return;
  const int j0 = jt*32, r0 = p*128;
  const int tid = threadIdx.x, lane = tid & 63, wave = tid >> 6;
  const int fr = lane & 15, fq = lane >> 4;
  f32x4 acc[4][2][2] = {};   // [0]=r(i+h), [1]=z(i+h), [2]=n-in, [3]=n-hid

  const unsigned short* sp[6]; int sdst[6];
  #pragma unroll
  for (int i = 0; i < 6; ++i) {
    int g = wave + 4*i;                 // 0..23
    int comp = g / 12, c = g - comp*12, rowgrp = c >> 2, q = c & 3;
    int R = rowgrp*64 + lane, gate = R>>5, jjj = R&31;
    int g3 = (gate >= 3) ? gate-3 : gate;
    int jcol = j0 + jjj; if (jcol > H-1) jcol = H-1;
    const unsigned short* base = (gate < 3) ? (comp ? Wihl : Wihh) : (comp ? Whhl : Whhh);
    sp[i] = base + (size_t)(g3*H + jcol)*KP + q*8;
    sdst[i] = comp*12288 + q*3072 + rowgrp*1024;
  }
  int arow[2];
  #pragma unroll
  for (int t = 0; t < 2; ++t) {
    int rg = r0 + wave*32 + t*16 + fr; if (rg > NN-1) rg = NN-1;
    arow[t] = rg*LPH + fq*8;
  }

  short8v Ac[4][2], An[4][2];   // [comp: g-hi, g-lo, h-hi, h-lo][t]
  #pragma unroll
  for (int i = 0; i < 6; ++i) gload16(sp[i], S[0] + sdst[i]);
  #pragma unroll
  for (int t = 0; t < 2; ++t) {
    Ac[0][t] = *(const short8v*)(Ghi + arow[t]);
    Ac[1][t] = *(const short8v*)(Glo + arow[t]);
    Ac[2][t] = *(const short8v*)(Hhi + arow[t]);
    Ac[3][t] = *(const short8v*)(Hlo + arow[t]);
  }
  __syncthreads();

  #pragma unroll
  for (int kk = 0; kk < 7; ++kk) {
    const int kb = kk & 1;
    if (kk < 6) {
      const int kn = (kk+1)*32;
      #pragma unroll
      for (int i = 0; i < 6; ++i) gload16(sp[i] + kn, S[kb^1] + sdst[i]);
      #pragma unroll
      for (int t = 0; t < 2; ++t) {
        An[0][t] = *(const short8v*)(Ghi + arow[t] + kn);
        An[1][t] = *(const short8v*)(Glo + arow[t] + kn);
        An[2][t] = *(const short8v*)(Hhi + arow[t] + kn);
        An[3][t] = *(const short8v*)(Hlo + arow[t] + kn);
      }
    }
    const char* w0 = S[kb] +     0 + fq*3072;
    const char* w1 = S[kb] + 12288 + fq*3072;
    #pragma unroll
    for (int g = 0; g < 6; ++g) {
      short8v b0h = *(const short8v*)(w0 + (g*32      + fr)*16);
      short8v b1h = *(const short8v*)(w0 + (g*32 + 16 + fr)*16);
      short8v b0l = *(const short8v*)(w1 + (g*32      + fr)*16);
      short8v b1l = *(const short8v*)(w1 + (g*32 + 16 + fr)*16);
      const int ai = (g < 3) ? 0 : 2;               // input path vs hidden path
      const int ac = (g == 5) ? 3 : (g % 3);        // r,z shared; n-in=2, n-hid=3
      #pragma unroll
      for (int t = 0; t < 2; ++t) {
        acc[ac][t][0] = MFMA16(Ac[ai][t],   b0h, acc[ac][t][0]);
        acc[ac][t][0] = MFMA16(Ac[ai][t],   b0l, acc[ac][t][0]);
        acc[ac][t][0] = MFMA16(Ac[ai+1][t], b0h, acc[ac][t][0]);
        acc[ac][t][1] = MFMA16(Ac[ai][t],   b1h, acc[ac][t][1]);
        acc[ac][t][1] = MFMA16(Ac[ai][t],   b1l, acc[ac][t][1]);
        acc[ac][t][1] = MFMA16(Ac[ai+1][t], b1h, acc[ac][t][1]);
      }
    }
    __syncthreads();
    if (kk < 6) {
      #pragma unroll
      for (int c2 = 0; c2 < 4; ++c2)
        #pragma unroll
        for (int t = 0; t < 2; ++t) Ac[c2][t] = An[c2][t];
    }
  }

  #pragma unroll
  for (int ct = 0; ct < 2; ++ct) {
    int j = j0 + ct*16 + fr;
    if (j >= LPH) continue;
    if (j >= H) {
      #pragma unroll
      for (int t = 0; t < 2; ++t)
        #pragma unroll
        for (int q = 0; q < 4; ++q) {
          int row = r0 + wave*32 + t*16 + fq*4 + q;
          if (row >= NN) continue;
          size_t o = (size_t)row*LPH + j;
          Ohi[o] = 0; Olo[o] = 0;
        }
      continue;
    }
    float br  = bih[j]     + bhh[j];
    float bz  = bih[H+j]   + bhh[H+j];
    float bin = bih[2*H+j], bhn = bhh[2*H+j];
    #pragma unroll
    for (int t = 0; t < 2; ++t)
      #pragma unroll
      for (int q = 0; q < 4; ++q) {
        int row = r0 + wave*32 + t*16 + fq*4 + q;
        if (row >= NN) continue;
        float rv = sigm(acc[0][t][ct][q] + br);
        float zv = sigm(acc[1][t][ct][q] + bz);
        float nv = tanhf(acc[2][t][ct][q] + bin + rv*(acc[3][t][ct][q] + bhn));
        size_t o = (size_t)row*LPH + j;
        float ho = uf(Hhi[o]) + uf(Hlo[o]);
        unsigned short hh2, ll2; split2((1.f - zv)*nv + zv*ho, hh2, ll2);
        Ohi[o] = hh2; Olo[o] = ll2;
      }
  }
}

// ---------------- CSR build ----------------
__global__ __launch_bounds__(256) void hist_k(const int* __restrict__ dst, int* __restrict__ deg){
  int e = blockIdx.x*256 + threadIdx.x;
  if (e < NE) atomicAdd(&deg[dst[e]], 1);
}

__global__ __launch_bounds__(256) void scan1_k(const int* __restrict__ deg, int* __restrict__ part,
                                               int* __restrict__ bsum, int n){
  __shared__ int lds[256];
  int t = threadIdx.x;
  int base = blockIdx.x * SCAN_B + t*4;
  int v[4]; int s = 0;
  #pragma unroll
  for (int q = 0; q < 4; ++q){ int idx = base+q; v[q] = (idx < n) ? deg[idx] : 0; s += v[q]; }
  lds[t] = s;
  __syncthreads();
  for (int off = 1; off < 256; off <<= 1){
    int val = 0;
    if (t >= off) val = lds[t-off];
    __syncthreads();
    if (t >= off) lds[t] += val;
    __syncthreads();
  }
  if (t == 255) bsum[blockIdx.x] = lds[255];
  int run = (t == 0) ? 0 : lds[t-1];
  #pragma unroll
  for (int q = 0; q < 4; ++q){ int idx = base+q; if (idx < n) part[idx] = run; run += v[q]; }
}

__global__ void scan2_k(int* __restrict__ bsum, int nb){
  __shared__ int lds[128];
  int t = threadIdx.x;
  int v = (t < nb) ? bsum[t] : 0;
  lds[t] = v;
  __syncthreads();
  for (int off = 1; off < 128; off <<= 1){
    int val = 0;
    if (t >= off) val = lds[t-off];
    __syncthreads();
    if (t >= off) lds[t] += val;
    __syncthreads();
  }
  if (t < nb) bsum[t] = (t == 0) ? 0 : lds[t-1];
}

__global__ __launch_bounds__(256) void scan3_k(const int* __restrict__ part, const int* __restrict__ bsum,
                                               int* __restrict__ rowptr, int* __restrict__ cpos, int n){
  int i = blockIdx.x*256 + threadIdx.x;
  if (i < n){
    int v = part[i] + bsum[i >> 10];
    rowptr[i] = v;
    cpos[i] = v;
  }
  if (i == 0) rowptr[n] = NE;
}

__global__ __launch_bounds__(256) void fill_k(const int* __restrict__ src, const int* __restrict__ dst,
                                              int* __restrict__ cpos, int* __restrict__ elist){
  int e = blockIdx.x*256 + threadIdx.x;
  if (e < NE){
    int p = atomicAdd(&cpos[dst[e]], 1);
    elist[p] = src[e];
  }
}

// ---------------- gather: GNB nodes/block, 2 nodes in flight (8 outstanding loads) ----
// Per-node chunk order & accumulator assignment identical to prior rounds -> bit-exact.
__global__ __launch_bounds__(256) void gather_k(const unsigned short* __restrict__ mhi,
                                                const unsigned short* __restrict__ mlo,
                                                const int* __restrict__ rowptr,
                                                const int* __restrict__ elist,
                                                unsigned short* __restrict__ ahi,
                                                unsigned short* __restrict__ alo){
  int j = threadIdx.x;
  if (j >= H) return;
  int nb = blockIdx.x * GNB;
  #pragma unroll
  for (int u = 0; u < GNB; u += 2){
    int nA = nb + u, nB = nb + u + 1;
    bool vA = nA < NN, vB = nB < NN;
    int kA = 0, eA = 0, kB = 0, eB = 0;
    if (vA){ kA = rowptr[nA]; eA = rowptr[nA+1]; }
    if (vB){ kB = rowptr[nB]; eB = rowptr[nB+1]; }
    float aA0=0.f,aA1=0.f,aA2=0.f,aA3=0.f;
    float aB0=0.f,aB1=0.f,aB2=0.f,aB3=0.f;
    // fused: both nodes advance together (independent chains -> 8 loads in flight)
    while (kA + 4 <= eA && kB + 4 <= eB){
      size_t sA0=(size_t)elist[kA  ]*LPH+j, sA1=(size_t)elist[kA+1]*LPH+j;
      size_t sA2=(size_t)elist[kA+2]*LPH+j, sA3=(size_t)elist[kA+3]*LPH+j;
      size_t sB0=(size_t)elist[kB  ]*LPH+j, sB1=(size_t)elist[kB+1]*LPH+j;
      size_t sB2=(size_t)elist[kB+2]*LPH+j, sB3=(size_t)elist[kB+3]*LPH+j;
      aA0 += uf(mhi[sA0]) + uf(mlo[sA0]);
      aA1 += uf(mhi[sA1]) + uf(mlo[sA1]);
      aA2 += uf(mhi[sA2]) + uf(mlo[sA2]);
      aA3 += uf(mhi[sA3]) + uf(mlo[sA3]);
      aB0 += uf(mhi[sB0]) + uf(mlo[sB0]);
      aB1 += uf(mhi[sB1]) + uf(mlo[sB1]);
      aB2 += uf(mhi[sB2]) + uf(mlo[sB2]);
      aB3 += uf(mhi[sB3]) + uf(mlo[sB3]);
      kA += 4; kB += 4;
    }
    for (; kA + 4 <= eA; kA += 4){
      size_t s0=(size_t)elist[kA  ]*LPH+j, s1=(size_t)elist[kA+1]*LPH+j;
      size_t s2=(size_t)elist[kA+2]*LPH+j, s3=(size_t)elist[kA+3]*LPH+j;
      aA0 += uf(mhi[s0]) + uf(mlo[s0]);
      aA1 += uf(mhi[s1]) + uf(mlo[s1]);
      aA2 += uf(mhi[s2]) + uf(mlo[s2]);
      aA3 += uf(mhi[s3]) + uf(mlo[s3]);
    }
    for (; kB + 4 <= eB; kB += 4){
      size_t s0=(size_t)elist[kB  ]*LPH+j, s1=(size_t)elist[kB+1]*LPH+j;
      size_t s2=(size_t)elist[kB+2]*LPH+j, s3=(size_t)elist[kB+3]*LPH+j;
      aB0 += uf(mhi[s0]) + uf(mlo[s0]);
      aB1 += uf(mhi[s1]) + uf(mlo[s1]);
      aB2 += uf(mhi[s2]) + uf(mlo[s2]);
      aB3 += uf(mhi[s3]) + uf(mlo[s3]);
    }
    for (; kA < eA; ++kA){
      size_t s = (size_t)elist[kA]*LPH + j;
      aA0 += uf(mhi[s]) + uf(mlo[s]);
    }
    for (; kB < eB; ++kB){
      size_t s = (size_t)elist[kB]*LPH + j;
      aB0 += uf(mhi[s]) + uf(mlo[s]);
    }
    if (vA){
      unsigned short hh, ll; split2((aA0 + aA1) + (aA2 + aA3), hh, ll);
      size_t o = (size_t)nA*LPH + j;
      ahi[o] = hh; alo[o] = ll;
    }
    if (vB){
      unsigned short hh, ll; split2((aB0 + aB1) + (aB2 + aB3), hh, ll);
      size_t o = (size_t)nB*LPH + j;
      ahi[o] = hh; alo[o] = ll;
    }
  }
}

// ---------------- pooling: 4 partial blocks per graph, then merge ----------------
__global__ __launch_bounds__(256) void pool_part(
    const unsigned short* __restrict__ hhi, const unsigned short* __restrict__ hlo,
    const int* __restrict__ batch,
    const float* __restrict__ g2, const float* __restrict__ b2,
    const float* __restrict__ m2, const float* __restrict__ v2,
    float* __restrict__ psum, float* __restrict__ pmax)
{
  int gb = blockIdx.x;
  int g = gb >> 2, c = gb & 3;
  int lo = 0, hi = NN;
  while (lo < hi){ int mid = (lo+hi)>>1; if (batch[mid] < g) lo = mid+1; else hi = mid; }
  int lo2 = lo, hi2 = NN;
  while (lo2 < hi2){ int mid = (lo2+hi2)>>1; if (batch[mid] < g+1) lo2 = mid+1; else hi2 = mid; }
  int cnt = hi2 - lo;
  int b0 = lo + (int)(((long)cnt * c) / 4);
  int b1 = lo + (int)(((long)cnt * (c+1)) / 4);
  int j = threadIdx.x;
  if (j >= H) return;
  float s = g2[j] * rsqrtf(v2[j] + EPSV);
  float mm = m2[j], bb = b2[j];
  float sum = 0.f, mx = 0.f;
  for (int n = b0; n < b1; ++n){
    size_t o = (size_t)n*LPH + j;
    float hv = uf(hhi[o]) + uf(hlo[o]);
    float val = fmaxf((hv - mm)*s + bb, 0.f);
    sum += val;
    mx = fmaxf(mx, val);
  }
  psum[(size_t)gb*H + j] = sum;
  pmax[(size_t)gb*H + j] = mx;
}

__global__ __launch_bounds__(256) void pool_merge(
    const float* __restrict__ psum, const float* __restrict__ pmax,
    const int* __restrict__ batch,
    float* __restrict__ gmean, float* __restrict__ gmax)
{
  int tid = blockIdx.x*256 + threadIdx.x;
  if (tid >= NG*H) return;
  int g = tid / H, j = tid - g*H;
  float s0 = psum[(size_t)(g*4+0)*H + j], s1 = psum[(size_t)(g*4+1)*H + j];
  float s2 = psum[(size_t)(g*4+2)*H + j], s3 = psum[(size_t)(g*4+3)*H + j];
  float m0 = pmax[(size_t)(g*4+0)*H + j], m1 = pmax[(size_t)(g*4+1)*H + j];
  float m2v = pmax[(size_t)(g*4+2)*H + j], m3 = pmax[(size_t)(g*4+3)*H + j];
  float sum = (s0 + s1) + (s2 + s3);
  float mx  = fmaxf(fmaxf(m0, m1), fmaxf(m2v, m3));
  int lo = 0, hi = NN;
  while (lo < hi){ int mid = (lo+hi)>>1; if (batch[mid] < g) lo = mid+1; else hi = mid; }
  int lo2 = lo, hi2 = NN;
  while (lo2 < hi2){ int mid = (lo2+hi2)>>1; if (batch[mid] < g+1) lo2 = mid+1; else hi2 = mid; }
  int c = hi2 - lo;
  gmean[tid] = (c > 0) ? sum/(float)c : 0.f;
  gmax [tid] = mx;
}

// ---------------- fc1 + bnf + relu ----------------
__global__ __launch_bounds__(256) void fc1_k(
    const float* __restrict__ gmean, const float* __restrict__ gmax,
    const float* __restrict__ W,
    const float* __restrict__ bias,
    const float* __restrict__ fg, const float* __restrict__ fb,
    const float* __restrict__ fm, const float* __restrict__ fv,
    float* __restrict__ out)
{
  int tid = blockIdx.x*256 + threadIdx.x;
  if (tid >= NG*H) return;
  int g = tid / H, j = tid - g*H;
  const float* wr = W + j*2*H;
  float acc = bias[j];
  for (int k = 0; k < H; ++k) acc += gmean[g*H + k] * wr[k];
  for (int k = 0; k < H; ++k) acc += gmax[g*H + k] * wr[H + k];
  float s = fg[j] * rsqrtf(fv[j] + EPSV);
  acc = (acc - fm[j]) * s + fb[j];
  out[tid] = fmaxf(acc, 0.f);
}

__global__ void fc2_k(const float* __restrict__ in, const float* __restrict__ W,
                      const float* __restrict__ bias, float* __restrict__ out)
{
  int tid = blockIdx.x*256 + threadIdx.x;
  if (tid >= NG*2) return;
  int g = tid >> 1, c = tid & 1;
  float acc = bias[c];
  const float* wr = W + c*H;
  const float* xr = in + g*H;
  for (int k = 0; k < H; ++k) acc += xr[k]*wr[k];
  out[tid] = acc;
}

extern "C" void kernel_launch(void* const* d_in, const int* in_sizes, int n_in,
                              void* d_out, int out_size, void* d_ws, size_t ws_size,
                              hipStream_t stream)
{
  const float* x     = (const float*)d_in[0];
  const int*   eidx  = (const int*)d_in[1];
  const int*   batch = (const int*)d_in[2];
  const float* projW = (const float*)d_in[3];
  const float* projb = (const float*)d_in[4];
  const float* bn1g  = (const float*)d_in[5];
  const float* bn1b  = (const float*)d_in[6];
  const float* bn1m  = (const float*)d_in[7];
  const float* bn1v  = (const float*)d_in[8];
  const float* bn2g  = (const float*)d_in[9];
  const float* bn2b  = (const float*)d_in[10];
  const float* bn2m  = (const float*)d_in[11];
  const float* bn2v  = (const float*)d_in[12];
  const float* bnfg  = (const float*)d_in[13];
  const float* bnfb  = (const float*)d_in[14];
  const float* bnfm  = (const float*)d_in[15];
  const float* bnfv  = (const float*)d_in[16];
  const float* ggcW  = (const float*)d_in[17];
  const float* wih   = (const float*)d_in[18];
  const float* whh   = (const float*)d_in[19];
  const float* bih   = (const float*)d_in[20];
  const float* bhh   = (const float*)d_in[21];
  const float* fc1W  = (const float*)d_in[22];
  const float* fc1b  = (const float*)d_in[23];
  const float* fc2W  = (const float*)d_in[24];
  const float* fc2b  = (const float*)d_in[25];

  char* wsp = (char*)d_ws;
  auto alloc = [&](size_t nbytes) {
    char* p = wsp;
    wsp += ((nbytes + 255) / 256) * 256;
    return (void*)p;
  };
  // Node tensors: three pair-regions (hi+lo contiguous) with zeroed 256B guards.
  const size_t PAIRE = (size_t)NN*LPH;            // elements per half
  unsigned short* xaHi = (unsigned short*)alloc(PAIRE*4);
  unsigned short* xaLo = xaHi + PAIRE;
  char* grd0 = (char*)alloc(256);
  unsigned short* hHi  = (unsigned short*)alloc(PAIRE*4);
  unsigned short* hLo  = hHi + PAIRE;
  char* grd1 = (char*)alloc(256);
  unsigned short* mHi  = (unsigned short*)alloc(PAIRE*4);
  unsigned short* mLo  = mHi + PAIRE;
  char* grd2 = (char*)alloc(256);
  // weights (bf16 split, zero-padded to KP)
  unsigned short* pBh   = (unsigned short*)alloc((size_t)H*KP*2);
  unsigned short* pBl   = (unsigned short*)alloc((size_t)H*KP*2);
  unsigned short* wihBh = (unsigned short*)alloc((size_t)3*H*KP*2);
  unsigned short* wihBl = (unsigned short*)alloc((size_t)3*H*KP*2);
  unsigned short* whhBh = (unsigned short*)alloc((size_t)3*H*KP*2);
  unsigned short* whhBl = (unsigned short*)alloc((size_t)3*H*KP*2);
  // per-step: ggc_W[i] non-transposed pair + fused weight Wf_i = wih @ G_i^T pair
  unsigned short* gNTh[3]; unsigned short* gNTl[3];
  unsigned short* wfBh[3]; unsigned short* wfBl[3];
  for (int i = 0; i < 3; ++i) {
    gNTh[i] = (unsigned short*)alloc((size_t)H*KP*2);
    gNTl[i] = (unsigned short*)alloc((size_t)H*KP*2);
    wfBh[i] = (unsigned short*)alloc((size_t)3*H*KP*2);
    wfBl[i] = (unsigned short*)alloc((size_t)3*H*KP*2);
  }
  float* wf32  = (float*)alloc((size_t)3*H*H*4);   // fp32 temp for fused weight
  float* gmean = (float*)alloc((size_t)NG*H*4);
  float* gmax  = (float*)alloc((size_t)NG*H*4);
  float* psum  = (float*)alloc((size_t)NG*4*H*4);
  float* pmax  = (float*)alloc((size_t)NG*4*H*4);
  float* fc1o  = (float*)alloc((size_t)NG*H*4);
  const int NB = (NN + SCAN_B - 1) / SCAN_B;
  int* deg    = (int*)alloc((size_t)NN*4);
  int* part   = (int*)alloc((size_t)NN*4);
  int* bsum   = (int*)alloc((size_t)NB*4);
  int* rowptr = (int*)alloc((size_t)(NN+1)*4);
  int* cpos   = (int*)alloc((size_t)NN*4);
  int* elist  = (int*)alloc((size_t)NE*4);

  const int* srcp = eidx;
  const int* dstp = eidx + NE;

  // zero the guards (overread landing zones)
  hipMemsetAsync(grd0, 0, 256, stream);
  hipMemsetAsync(grd1, 0, 256, stream);
  hipMemsetAsync(grd2, 0, 256, stream);

  // ---- CSR build (reused all 3 steps) ----
  hipMemsetAsync(deg, 0, (size_t)NN*4, stream);
  hist_k<<<(NE + 255)/256, 256, 0, stream>>>(dstp, deg);
  scan1_k<<<NB, 256, 0, stream>>>(deg, part, bsum, NN);
  scan2_k<<<1, 128, 0, stream>>>(bsum, NB);
  scan3_k<<<(NN + 255)/256, 256, 0, stream>>>(part, bsum, rowptr, cpos, NN);
  fill_k<<<(NE + 255)/256, 256, 0, stream>>>(srcp, dstp, cpos, elist);

  // ---- weight splits (pitch KP, zero-padded) ----
  cvt_split<<<(int)(((long)H*KP + 255)/256), 256, 0, stream>>>(projW, pBh, pBl, H, D, KP);
  cvt_split<<<(int)(((long)3*H*KP + 255)/256), 256, 0, stream>>>(wih, wihBh, wihBl, 3*H, H, KP);
  cvt_split<<<(int)(((long)3*H*KP + 255)/256), 256, 0, stream>>>(whh, whhBh, whhBl, 3*H, H, KP);
  for (int i = 0; i < 3; ++i)
    cvt_split<<<(int)(((long)H*KP + 255)/256), 256, 0, stream>>>(ggcW + (size_t)i*H*H,
                                                                 gNTh[i], gNTl[i], H, H, KP);

  // ---- x -> split pair (pitch LPH, zero-padded pads) ----
  cvt_split<<<(int)(((long)NN*LPH + 255)/256), 256, 0, stream>>>(x, xaHi, xaLo, NN, D, LPH);

  // XCD-grouped grids
  const int NPAN = (NN + 127)/128;            // 782
  const int PL8  = (NPAN + 7)/8;              // 98
  const int NJ_G = (H + 127)/128;             // 2
  const int NJ_U = (H + 31)/32;               // 7
  const int GRID_G = 8 * NJ_G * PL8;
  const int GRID_U = 8 * NJ_U * PL8;
  const int NPANW = (3*H + 127)/128;          // 5
  const int GRID_W = 8 * NJ_G * ((NPANW + 7)/8);

  // ---- fused weights: Wf_i = wih @ G_i^T ----
  for (int i = 0; i < 3; ++i) {
    mgemm<0><<<GRID_W, 256, 0, stream>>>(wihBh, wihBl, gNTh[i], gNTl[i],
                                         3*H, H, NJ_G, NPANW, KP, H,
                                         nullptr, nullptr, nullptr, nullptr, nullptr,
                                         nullptr, nullptr, wf32);
    cvt_split<<<(int)(((long)3*H*KP + 255)/256), 256, 0, stream>>>(wf32, wfBh[i], wfBl[i],
                                                                   3*H, H, KP);
  }

  // proj + bn1 + relu : xpair -> hpair (pads zeroed by epilogue)
  mgemm<1><<<GRID_G, 256, 0, stream>>>(xaHi, xaLo, pBh, pBl, NN, H, NJ_G, NPAN, LPH, 0,
                                       projb, bn1g, bn1b, bn1m, bn1v, hHi, hLo, nullptr);

  unsigned short *chHi = hHi, *chLo = hLo, *cmHi = mHi, *cmLo = mLo;
  for (int i = 0; i < 3; ++i) {
    gather_k<<<(NN + GNB - 1)/GNB, 256, 0, stream>>>(chHi, chLo, rowptr, elist, xaHi, xaLo);
    gru6<<<GRID_U, 256, 0, stream>>>(xaHi, xaLo, chHi, chLo,
                                     wfBh[i], wfBl[i], whhBh, whhBl,
                                     bih, bhh, NJ_U, NPAN, cmHi, cmLo);
    unsigned short* t;
    t = chHi; chHi = cmHi; cmHi = t;
    t = chLo; chLo = cmLo; cmLo = t;
  }

  pool_part<<<NG*4, 256, 0, stream>>>(chHi, chLo, batch, bn2g, bn2b, bn2m, bn2v, psum, pmax);
  pool_merge<<<(NG*H + 255)/256, 256, 0, stream>>>(psum, pmax, batch, gmean, gmax);
  fc1_k<<<(NG*H + 255)/256, 256, 0, stream>>>(gmean, gmax, fc1W, fc1b,
                                              bnfg, bnfb, bnfm, bnfv, fc1o);
  fc2_k<<<(NG*2 + 255)/256, 256, 0, stream>>>(fc1o, fc2W, fc2b, (float*)d_out);
}